// Round 7
// baseline (879.753 us; speedup 1.0000x reference)
//
#include <hip/hip_runtime.h>
#include <math.h>

#define D_    1024
#define ED_   2048
#define NST   32
#define KCONV 4
#define DTR_  64
#define L_    1024
#define NB_   4
#define NCH   8
#define CHUNK (L_ / NCH)
#define KSPL  8
#define ZSPL  4

typedef __bf16 bf16_8 __attribute__((ext_vector_type(8)));
typedef __bf16 bf16_4 __attribute__((ext_vector_type(4)));
typedef float  f32x4  __attribute__((ext_vector_type(4)));

__device__ __forceinline__ float softplus_f(float x) {
  return x > 20.f ? x : log1pf(expf(x));
}
__device__ __forceinline__ float silu_f(float x) {
  return x / (1.f + expf(-x));
}

// fp32 -> bf16 (n multiple of 2048)
__global__ __launch_bounds__(256) void f2bf_k(
    const float* __restrict__ in, __bf16* __restrict__ out, int n)
{
  const int i = (blockIdx.x * 256 + threadIdx.x) * 8;
  if (i >= n) return;
  const float4 a = *reinterpret_cast<const float4*>(in + i);
  const float4 b = *reinterpret_cast<const float4*>(in + i + 4);
  bf16_8 v;
  v[0]=(__bf16)a.x; v[1]=(__bf16)a.y; v[2]=(__bf16)a.z; v[3]=(__bf16)a.w;
  v[4]=(__bf16)b.x; v[5]=(__bf16)b.y; v[6]=(__bf16)b.z; v[7]=(__bf16)b.w;
  *reinterpret_cast<bf16_8*>(out + i) = v;
}

// ---- MFMA bf16 GEMM: C[M,N] = A[M,K](lda) @ W[N,K](ldw)^T ----
// 128x128 tile, BK=32, 4 waves; flags: 1=accumulate, 2=softplus, 4=bias
__global__ __launch_bounds__(256) void gemm_mfma(
    const __bf16* __restrict__ A, int lda,
    const __bf16* __restrict__ W, int ldw,
    const float* __restrict__ bias, float* __restrict__ C, int ldc,
    int K, int flags)
{
  __shared__ __bf16 As[128 * 32];
  __shared__ __bf16 Ws[128 * 32];
  const int tid  = threadIdx.x;
  const int lane = tid & 63;
  const int w    = tid >> 6;
  const int wr   = w >> 1, wc = w & 1;
  const int row0 = blockIdx.y * 128, col0 = blockIdx.x * 128;

  f32x4 acc[4][4] = {};

  for (int k0 = 0; k0 < K; k0 += 32) {
    #pragma unroll
    for (int j = 0; j < 2; ++j) {
      const int inst = w * 2 + j;
      const int eo   = inst * 512 + lane * 8;
      const int r    = eo >> 5, k = eo & 31;
      __builtin_amdgcn_global_load_lds(
          (const __attribute__((address_space(1))) void*)(A + (size_t)(row0 + r) * lda + k0 + k),
          (__attribute__((address_space(3))) void*)(&As[inst * 512]), 16, 0, 0);
      __builtin_amdgcn_global_load_lds(
          (const __attribute__((address_space(1))) void*)(W + (size_t)(col0 + r) * ldw + k0 + k),
          (__attribute__((address_space(3))) void*)(&Ws[inst * 512]), 16, 0, 0);
    }
    __syncthreads();
    bf16_8 af[4], bfr[4];
    const int kk  = (lane >> 4) * 8;
    const int r16 = lane & 15;
    #pragma unroll
    for (int m = 0; m < 4; ++m)
      af[m] = *reinterpret_cast<const bf16_8*>(&As[(wr * 64 + m * 16 + r16) * 32 + kk]);
    #pragma unroll
    for (int n = 0; n < 4; ++n)
      bfr[n] = *reinterpret_cast<const bf16_8*>(&Ws[(wc * 64 + n * 16 + r16) * 32 + kk]);
    #pragma unroll
    for (int m = 0; m < 4; ++m)
      #pragma unroll
      for (int n = 0; n < 4; ++n)
        acc[m][n] = __builtin_amdgcn_mfma_f32_16x16x32_bf16(af[m], bfr[n], acc[m][n], 0, 0, 0);
    __syncthreads();
  }

  const int crow = (lane >> 4) * 4;
  const int ccol = lane & 15;
  #pragma unroll
  for (int m = 0; m < 4; ++m)
    #pragma unroll
    for (int n = 0; n < 4; ++n) {
      const int col = col0 + wc * 64 + n * 16 + ccol;
      const float bv = (flags & 4) ? bias[col] : 0.f;
      #pragma unroll
      for (int r = 0; r < 4; ++r) {
        const int row = row0 + wr * 64 + m * 16 + crow + r;
        float* cp = C + (size_t)row * ldc + col;
        float v = acc[m][n][r] + bv;
        if (flags & 2) v = softplus_f(v);
        if (flags & 1) v += *cp;
        *cp = v;
      }
    }
}

// split-K MFMA GEMM: partials[z][M][N] = A[:, z*Kc:(z+1)*Kc] @ W^T chunk (lda=ldw=K)
__global__ __launch_bounds__(256) void gemm_mfma_sk(
    const __bf16* __restrict__ A, const __bf16* __restrict__ W,
    float* __restrict__ partials, int M, int N, int K, int Kc)
{
  __shared__ __bf16 As[128 * 32];
  __shared__ __bf16 Ws[128 * 32];
  const int tid  = threadIdx.x;
  const int lane = tid & 63;
  const int w    = tid >> 6;
  const int wr   = w >> 1, wc = w & 1;
  const int row0 = blockIdx.y * 128, col0 = blockIdx.x * 128;
  const int kbase = blockIdx.z * Kc;

  f32x4 acc[4][4] = {};

  for (int k0 = kbase; k0 < kbase + Kc; k0 += 32) {
    #pragma unroll
    for (int j = 0; j < 2; ++j) {
      const int inst = w * 2 + j;
      const int eo   = inst * 512 + lane * 8;
      const int r    = eo >> 5, k = eo & 31;
      __builtin_amdgcn_global_load_lds(
          (const __attribute__((address_space(1))) void*)(A + (size_t)(row0 + r) * K + k0 + k),
          (__attribute__((address_space(3))) void*)(&As[inst * 512]), 16, 0, 0);
      __builtin_amdgcn_global_load_lds(
          (const __attribute__((address_space(1))) void*)(W + (size_t)(col0 + r) * K + k0 + k),
          (__attribute__((address_space(3))) void*)(&Ws[inst * 512]), 16, 0, 0);
    }
    __syncthreads();
    bf16_8 af[4], bfr[4];
    const int kk  = (lane >> 4) * 8;
    const int r16 = lane & 15;
    #pragma unroll
    for (int m = 0; m < 4; ++m)
      af[m] = *reinterpret_cast<const bf16_8*>(&As[(wr * 64 + m * 16 + r16) * 32 + kk]);
    #pragma unroll
    for (int n = 0; n < 4; ++n)
      bfr[n] = *reinterpret_cast<const bf16_8*>(&Ws[(wc * 64 + n * 16 + r16) * 32 + kk]);
    #pragma unroll
    for (int m = 0; m < 4; ++m)
      #pragma unroll
      for (int n = 0; n < 4; ++n)
        acc[m][n] = __builtin_amdgcn_mfma_f32_16x16x32_bf16(af[m], bfr[n], acc[m][n], 0, 0, 0);
    __syncthreads();
  }

  float* base = partials + (size_t)blockIdx.z * M * N;
  const int crow = (lane >> 4) * 4;
  const int ccol = lane & 15;
  #pragma unroll
  for (int m = 0; m < 4; ++m)
    #pragma unroll
    for (int n = 0; n < 4; ++n) {
      const int col = col0 + wc * 64 + n * 16 + ccol;
      #pragma unroll
      for (int r = 0; r < 4; ++r) {
        const int row = row0 + wr * 64 + m * 16 + crow + r;
        base[(size_t)row * N + col] = acc[m][n][r];
      }
    }
}

// reduce ZSPL partials -> C; flags: 1=accumulate into C, 4=bias (per column)
__global__ __launch_bounds__(256) void mfma_sk_reduce(
    const float* __restrict__ partials, const float* __restrict__ bias,
    float* __restrict__ C, int elems, int ncols, int flags)
{
  const int i = (blockIdx.x * 256 + threadIdx.x) * 4;
  if (i >= elems) return;
  float4 s = *reinterpret_cast<const float4*>(partials + i);
  #pragma unroll
  for (int z = 1; z < ZSPL; ++z) {
    const float4 p = *reinterpret_cast<const float4*>(partials + (size_t)z * elems + i);
    s.x += p.x; s.y += p.y; s.z += p.z; s.w += p.w;
  }
  if (flags & 4) {
    const float4 bv = *reinterpret_cast<const float4*>(bias + (i % ncols));
    s.x += bv.x; s.y += bv.y; s.z += bv.z; s.w += bv.w;
  }
  if (flags & 1) {
    const float4 ov = *reinterpret_cast<const float4*>(C + i);
    s.x += ov.x; s.y += ov.y; s.z += ov.z; s.w += ov.w;
  }
  *reinterpret_cast<float4*>(C + i) = s;
}

// split-K fp32 GEMM (xproj)
__global__ __launch_bounds__(256) void gemm_bt_sk(
    const float* __restrict__ A, int lda,
    const float* __restrict__ W, int ldw,
    float* __restrict__ partials, int ldc,
    int M, int N, int K)
{
  __shared__ float As[16][65];
  __shared__ float Ws[16][65];
  const int tid = threadIdx.x;
  const int row0 = blockIdx.y * 64, col0 = blockIdx.x * 64;
  const int Kc = K / KSPL;
  const int kbase = blockIdx.z * Kc;
  const int tx = tid & 15, ty = tid >> 4;
  const int lm = tid >> 2, lk = (tid & 3) << 2;
  float acc[4][4] = {};
  for (int k0 = kbase; k0 < kbase + Kc; k0 += 16) {
    float4 av = *reinterpret_cast<const float4*>(A + (size_t)(row0 + lm) * lda + k0 + lk);
    float4 wv = *reinterpret_cast<const float4*>(W + (size_t)(col0 + lm) * ldw + k0 + lk);
    __syncthreads();
    As[lk+0][lm]=av.x; As[lk+1][lm]=av.y; As[lk+2][lm]=av.z; As[lk+3][lm]=av.w;
    Ws[lk+0][lm]=wv.x; Ws[lk+1][lm]=wv.y; Ws[lk+2][lm]=wv.z; Ws[lk+3][lm]=wv.w;
    __syncthreads();
    #pragma unroll
    for (int k = 0; k < 16; ++k) {
      float a0 = As[k][ty*4+0], a1 = As[k][ty*4+1], a2 = As[k][ty*4+2], a3 = As[k][ty*4+3];
      float b0 = Ws[k][tx*4+0], b1 = Ws[k][tx*4+1], b2 = Ws[k][tx*4+2], b3 = Ws[k][tx*4+3];
      acc[0][0] += a0*b0; acc[0][1] += a0*b1; acc[0][2] += a0*b2; acc[0][3] += a0*b3;
      acc[1][0] += a1*b0; acc[1][1] += a1*b1; acc[1][2] += a1*b2; acc[1][3] += a1*b3;
      acc[2][0] += a2*b0; acc[2][1] += a2*b1; acc[2][2] += a2*b2; acc[2][3] += a2*b3;
      acc[3][0] += a3*b0; acc[3][1] += a3*b1; acc[3][2] += a3*b2; acc[3][3] += a3*b3;
    }
  }
  float* base = partials + (size_t)blockIdx.z * M * ldc;
  #pragma unroll
  for (int i = 0; i < 4; ++i) {
    const int r = row0 + ty*4 + i;
    float4 v = make_float4(acc[i][0], acc[i][1], acc[i][2], acc[i][3]);
    *reinterpret_cast<float4*>(base + (size_t)r * ldc + col0 + tx*4) = v;
  }
}

// reduce KSPL partials -> C (fp32) and Cbf (bf16 copy, feeds dt MFMA GEMM)
__global__ __launch_bounds__(256) void sk_reduce_k(
    const float* __restrict__ partials, float* __restrict__ C,
    __bf16* __restrict__ Cbf, int elems)
{
  const int i = (blockIdx.x * 256 + threadIdx.x) * 4;
  if (i >= elems) return;
  float4 s = *reinterpret_cast<const float4*>(partials + i);
  #pragma unroll
  for (int z = 1; z < KSPL; ++z) {
    const float4 p = *reinterpret_cast<const float4*>(partials + (size_t)z * elems + i);
    s.x += p.x; s.y += p.y; s.z += p.z; s.w += p.w;
  }
  *reinterpret_cast<float4*>(C + i) = s;
  bf16_4 b;
  b[0]=(__bf16)s.x; b[1]=(__bf16)s.y; b[2]=(__bf16)s.z; b[3]=(__bf16)s.w;
  *reinterpret_cast<bf16_4*>(Cbf + i) = b;
}

// layernorm, fp32 out (final LN)
__global__ __launch_bounds__(256) void layernorm_k(
    const float* __restrict__ x, const float* __restrict__ g,
    const float* __restrict__ b, float* __restrict__ out)
{
  __shared__ float red[8];
  const int row = blockIdx.x;
  const int tid = threadIdx.x;
  const float* xr = x + (size_t)row * D_;
  float4 v = *reinterpret_cast<const float4*>(xr + tid * 4);
  float s = v.x + v.y + v.z + v.w;
  #pragma unroll
  for (int off = 32; off; off >>= 1) s += __shfl_down(s, off, 64);
  if ((tid & 63) == 0) red[tid >> 6] = s;
  __syncthreads();
  const float m = (red[0] + red[1] + red[2] + red[3]) * (1.f / D_);
  float dx0 = v.x - m, dx1 = v.y - m, dx2 = v.z - m, dx3 = v.w - m;
  float ss = dx0*dx0 + dx1*dx1 + dx2*dx2 + dx3*dx3;
  #pragma unroll
  for (int off = 32; off; off >>= 1) ss += __shfl_down(ss, off, 64);
  if ((tid & 63) == 0) red[4 + (tid >> 6)] = ss;
  __syncthreads();
  const float var = (red[4] + red[5] + red[6] + red[7]) * (1.f / D_);
  const float rs = rsqrtf(var + 1e-5f);
  const int c = tid * 4;
  const float4 gv = *reinterpret_cast<const float4*>(g + c);
  const float4 bv = *reinterpret_cast<const float4*>(b + c);
  float4 o;
  o.x = dx0 * rs * gv.x + bv.x;
  o.y = dx1 * rs * gv.y + bv.y;
  o.z = dx2 * rs * gv.z + bv.z;
  o.w = dx3 * rs * gv.w + bv.w;
  *reinterpret_cast<float4*>(out + (size_t)row * D_ + c) = o;
}

// layernorm with bf16 out (feeds MFMA GEMM)
__global__ __launch_bounds__(256) void layernorm_bf_k(
    const float* __restrict__ x, const float* __restrict__ g,
    const float* __restrict__ b, __bf16* __restrict__ out)
{
  __shared__ float red[8];
  const int row = blockIdx.x;
  const int tid = threadIdx.x;
  const float* xr = x + (size_t)row * D_;
  float4 v = *reinterpret_cast<const float4*>(xr + tid * 4);
  float s = v.x + v.y + v.z + v.w;
  #pragma unroll
  for (int off = 32; off; off >>= 1) s += __shfl_down(s, off, 64);
  if ((tid & 63) == 0) red[tid >> 6] = s;
  __syncthreads();
  const float m = (red[0] + red[1] + red[2] + red[3]) * (1.f / D_);
  float dx0 = v.x - m, dx1 = v.y - m, dx2 = v.z - m, dx3 = v.w - m;
  float ss = dx0*dx0 + dx1*dx1 + dx2*dx2 + dx3*dx3;
  #pragma unroll
  for (int off = 32; off; off >>= 1) ss += __shfl_down(ss, off, 64);
  if ((tid & 63) == 0) red[4 + (tid >> 6)] = ss;
  __syncthreads();
  const float var = (red[4] + red[5] + red[6] + red[7]) * (1.f / D_);
  const float rs = rsqrtf(var + 1e-5f);
  const int c = tid * 4;
  const float4 gv = *reinterpret_cast<const float4*>(g + c);
  const float4 bv = *reinterpret_cast<const float4*>(b + c);
  bf16_4 o;
  o[0] = (__bf16)(dx0 * rs * gv.x + bv.x);
  o[1] = (__bf16)(dx1 * rs * gv.y + bv.y);
  o[2] = (__bf16)(dx2 * rs * gv.z + bv.z);
  o[3] = (__bf16)(dx3 * rs * gv.w + bv.w);
  *reinterpret_cast<bf16_4*>(out + (size_t)row * D_ + c) = o;
}

// depthwise causal conv K=4 + bias + silu
__global__ __launch_bounds__(256) void conv_silu_k(
    const float* __restrict__ xz, const float* __restrict__ cw,
    const float* __restrict__ cb, float* __restrict__ u)
{
  const int e = blockIdx.x * 256 + threadIdx.x;
  const int t = blockIdx.y;
  const float w0 = cw[e*4+0], w1 = cw[e*4+1], w2 = cw[e*4+2], w3 = cw[e*4+3];
  float acc = cb[e];
  if (t >= 3) acc += w0 * xz[(size_t)(t-3) * (2*ED_) + e];
  if (t >= 2) acc += w1 * xz[(size_t)(t-2) * (2*ED_) + e];
  if (t >= 1) acc += w2 * xz[(size_t)(t-1) * (2*ED_) + e];
  acc += w3 * xz[(size_t)t * (2*ED_) + e];
  u[(size_t)t * ED_ + e] = silu_f(acc);
}

// ---- chunked selective scan ----
__global__ __launch_bounds__(256) void scan_phase1(
    const float* __restrict__ delta, const float* __restrict__ u,
    const float* __restrict__ xdbl, const float* __restrict__ A_log,
    float* __restrict__ hend, float* __restrict__ Pend)
{
  const int tid = threadIdx.x;
  const int n = tid & 31;
  const int e = blockIdx.x * 8 + (tid >> 5);
  const int c = blockIdx.y;
  const float a = -expf(A_log[e * NST + n]);
  float h = 0.f, S = 0.f;
  const int t0 = c * CHUNK;
  #pragma unroll 8
  for (int t = t0; t < t0 + CHUNK; ++t) {
    const float sd = delta[(size_t)t * ED_ + e];
    const float uv = u[(size_t)t * ED_ + e];
    const float Bv = xdbl[(size_t)t * 128 + 64 + n];
    const float dA = __expf(sd * a);
    h = fmaf(dA, h, sd * uv * Bv);
    S += sd;
  }
  const int idx = c * (ED_ * NST) + blockIdx.x * 256 + tid;
  hend[idx] = h;
  Pend[idx] = __expf(a * S);
}

__global__ __launch_bounds__(256) void scan_phase2(
    const float* __restrict__ hend, float* __restrict__ Pend_hin)
{
  const int idx = blockIdx.x * 256 + threadIdx.x;
  float hc = 0.f;
  #pragma unroll
  for (int c = 0; c < NCH; ++c) {
    const int off = c * (ED_ * NST) + idx;
    const float P = Pend_hin[off];
    const float hn = hend[off];
    Pend_hin[off] = hc;
    hc = fmaf(P, hc, hn);
  }
}

// phase 3: re-scan from true h_in; 16-step LDS deferred n-reduction.
// LDS 16.9KB -> 8 blocks/CU (100% occupancy at __launch_bounds__(256,8)).
__global__ __launch_bounds__(256, 8) void scan_phase3(
    const float* __restrict__ delta, const float* __restrict__ u,
    const float* __restrict__ xdbl, const float* __restrict__ A_log,
    const float* __restrict__ hin, const float* __restrict__ Dp,
    const float* __restrict__ xz, __bf16* __restrict__ y)
{
  __shared__ float p_lds[8][16][33];
  const int tid = threadIdx.x;
  const int n = tid & 31;
  const int c = tid >> 5;
  const int e = blockIdx.x * 8 + c;
  const int ch = blockIdx.y;
  const float a = -expf(A_log[e * NST + n]);
  const float dp = Dp[e];
  float h = hin[ch * (ED_ * NST) + blockIdx.x * 256 + tid];
  const int t0 = ch * CHUNK;
  const int r    = n & 15;
  const int half = n >> 4;
  for (int tb = 0; tb < CHUNK; tb += 16) {
    #pragma unroll 4
    for (int j = 0; j < 16; ++j) {
      const int t = t0 + tb + j;
      const float sd = delta[(size_t)t * ED_ + e];
      const float uv = u[(size_t)t * ED_ + e];
      const float Bv = xdbl[(size_t)t * 128 + 64 + n];
      const float Cv = xdbl[(size_t)t * 128 + 96 + n];
      const float dA = __expf(sd * a);
      h = fmaf(dA, h, sd * uv * Bv);
      p_lds[c][j][n] = h * Cv;
    }
    __syncthreads();
    float s = 0.f;
    #pragma unroll
    for (int k = 0; k < 16; ++k) s += p_lds[c][r][half * 16 + k];
    s += __shfl_xor(s, 16, 64);
    if (half == 0) {
      const int t = t0 + tb + r;
      const float uvt = u[(size_t)t * ED_ + e];
      const float zv = xz[(size_t)t * (2*ED_) + ED_ + e];
      y[(size_t)t * ED_ + e] = (__bf16)((s + uvt * dp) * silu_f(zv));
    }
    __syncthreads();
  }
}

__global__ __launch_bounds__(256) void colmean_k(const float* __restrict__ hf, float* __restrict__ cm)
{
  const int d = blockIdx.x * 256 + threadIdx.x;
  float s = 0.f;
  for (int t = 0; t < L_; ++t) s += hf[(size_t)t * D_ + d];
  cm[d] = s * (1.f / L_);
}

__global__ __launch_bounds__(256) void state_k(
    const float* __restrict__ cm, const float* __restrict__ spw,
    const float* __restrict__ spb, float* __restrict__ out)
{
  __shared__ float red[4];
  const int nidx = blockIdx.x;
  const int tid = threadIdx.x;
  float s = 0.f;
  for (int d = tid; d < D_; d += 256) s += cm[d] * spw[(size_t)nidx * D_ + d];
  #pragma unroll
  for (int off = 32; off; off >>= 1) s += __shfl_down(s, off, 64);
  if ((tid & 63) == 0) red[tid >> 6] = s;
  __syncthreads();
  if (tid == 0) out[nidx] = red[0] + red[1] + red[2] + red[3] + spb[nidx];
}

extern "C" void kernel_launch(void* const* d_in, const int* in_sizes, int n_in,
                              void* d_out, int out_size, void* d_ws, size_t ws_size,
                              hipStream_t stream) {
  const float* x        = (const float*)d_in[0];
  const float* Wi       = (const float*)d_in[1];
  const float* bi       = (const float*)d_in[2];
  const float* ln_g     = (const float*)d_in[3];
  const float* ln_b     = (const float*)d_in[4];
  const float* in_w     = (const float*)d_in[5];
  const float* conv_w   = (const float*)d_in[6];
  const float* conv_b   = (const float*)d_in[7];
  const float* xproj_w  = (const float*)d_in[8];
  const float* dtproj_w = (const float*)d_in[9];
  const float* dtproj_b = (const float*)d_in[10];
  const float* A_log    = (const float*)d_in[11];
  const float* Dp       = (const float*)d_in[12];
  const float* out_w    = (const float*)d_in[13];
  const float* fn_g     = (const float*)d_in[14];
  const float* fn_b     = (const float*)d_in[15];
  const float* sp_w     = (const float*)d_in[16];
  const float* sp_b     = (const float*)d_in[17];
  float* out  = (float*)d_out;
  float* ws_f = (float*)d_ws;

  float* h_buf  = ws_f;                // 1048576
  float* xz     = ws_f + 1048576;      // 4194304
  float* u_buf  = ws_f + 5242880;      // 2097152
  float* xdbl   = ws_f + 7340032;      // 131072
  float* delta  = ws_f + 7471104;      // 2097152
  float* hend   = ws_f + 9568256;      // 524288
  float* pend   = ws_f + 10092544;     // 524288
  float* cmean  = ws_f + 10616832;     // 1024
  __bf16* nbf   = (__bf16*)(ws_f + 10617856);  // 1M bf16 (524288 f)
  __bf16* ybf   = (__bf16*)(ws_f + 11142144);  // 2M bf16 (1048576 f)
  __bf16* wbf   = (__bf16*)(ws_f + 12190720);  // 8M bf16 (4194304 f)
  __bf16* xdblbf= (__bf16*)(ws_f + 16385024);  // 128K bf16 (65536 f)
  __bf16* dtwbf = (__bf16*)(ws_f + 16450560);  // 128K bf16 (65536 f)
  // xproj split-K partials: overlays hend+pend (dead until scan_phase1)
  float* skpart = hend;                // KSPL * 1024 * 128 = 1048576
  // MFMA split-K partials: overlays u_buf/xdbl/delta (dead at both use-sites)
  float* skmf   = u_buf;               // 4 * 1048576 floats

  const dim3 blk(256);

  // h = x @ Wi^T + bi   (bf16 MFMA, split-K=4)
  f2bf_k<<<512, blk, 0, stream>>>(x, nbf, L_ * D_);
  f2bf_k<<<512, blk, 0, stream>>>(Wi, wbf, D_ * D_);
  gemm_mfma_sk<<<dim3(D_/128, L_/128, ZSPL), blk, 0, stream>>>(
      nbf, wbf, skmf, L_, D_, D_, D_/ZSPL);
  mfma_sk_reduce<<<dim3(L_*D_/4/256), blk, 0, stream>>>(
      skmf, bi, h_buf, L_*D_, D_, 4);

  for (int i = 0; i < NB_; ++i) {
    layernorm_bf_k<<<L_, blk, 0, stream>>>(h_buf, ln_g + i*D_, ln_b + i*D_, nbf);
    // xz = normed @ in_w^T
    f2bf_k<<<2048, blk, 0, stream>>>(in_w + (size_t)i*2*ED_*D_, wbf, 2*ED_*D_);
    gemm_mfma<<<dim3(2*ED_/128, L_/128), blk, 0, stream>>>(
        nbf, D_, wbf, D_, nullptr, xz, 2*ED_, D_, 0);
    conv_silu_k<<<dim3(ED_/256, L_), blk, 0, stream>>>(
        xz, conv_w + (size_t)i*ED_*KCONV, conv_b + (size_t)i*ED_, u_buf);
    // x_dbl = u @ xproj^T  (fp32 split-K over 8 chunks; emits fp32 + bf16)
    gemm_bt_sk<<<dim3(128/64, L_/64, KSPL), blk, 0, stream>>>(
        u_buf, ED_, xproj_w + (size_t)i*128*ED_, ED_, skpart, 128, L_, 128, ED_);
    sk_reduce_k<<<dim3(L_*128/4/256), blk, 0, stream>>>(skpart, xdbl, xdblbf, L_ * 128);
    // delta = softplus(dt @ dtproj^T + b)  (bf16 MFMA, K=64)
    f2bf_k<<<64, blk, 0, stream>>>(dtproj_w + (size_t)i*ED_*DTR_, dtwbf, ED_*DTR_);
    gemm_mfma<<<dim3(ED_/128, L_/128), blk, 0, stream>>>(
        xdblbf, 128, dtwbf, DTR_, dtproj_b + (size_t)i*ED_, delta, ED_, DTR_, 2 | 4);
    // chunked scan
    scan_phase1<<<dim3(ED_/8, NCH), blk, 0, stream>>>(
        delta, u_buf, xdbl, A_log + (size_t)i*ED_*NST, hend, pend);
    scan_phase2<<<dim3(ED_*NST/256), blk, 0, stream>>>(hend, pend);
    scan_phase3<<<dim3(ED_/8, NCH), blk, 0, stream>>>(
        delta, u_buf, xdbl, A_log + (size_t)i*ED_*NST, pend,
        Dp + (size_t)i*ED_, xz, ybf);
    // h += y @ out_w^T   (bf16 MFMA, split-K=4)
    f2bf_k<<<1024, blk, 0, stream>>>(out_w + (size_t)i*D_*ED_, wbf, D_*ED_);
    gemm_mfma_sk<<<dim3(D_/128, L_/128, ZSPL), blk, 0, stream>>>(
        ybf, wbf, skmf, L_, D_, ED_, ED_/ZSPL);
    mfma_sk_reduce<<<dim3(L_*D_/4/256), blk, 0, stream>>>(
        skmf, nullptr, h_buf, L_*D_, D_, 1);
  }

  layernorm_k<<<L_, blk, 0, stream>>>(h_buf, fn_g, fn_b, out);
  colmean_k<<<D_/256, blk, 0, stream>>>(out, cmean);
  state_k<<<NST, blk, 0, stream>>>(cmean, sp_w, sp_b, out + (size_t)L_*D_);
}

// Round 8
// 789.129 us; speedup vs baseline: 1.1148x; 1.1148x over previous
//
#include <hip/hip_runtime.h>
#include <math.h>

#define D_    1024
#define ED_   2048
#define NST   32
#define KCONV 4
#define DTR_  64
#define L_    1024
#define NB_   4
#define NCH   8
#define CHUNK (L_ / NCH)
#define KSPL  8
#define ZSPL  4

typedef __bf16 bf16_8 __attribute__((ext_vector_type(8)));
typedef __bf16 bf16_4 __attribute__((ext_vector_type(4)));
typedef float  f32x4  __attribute__((ext_vector_type(4)));

__device__ __forceinline__ float softplus_f(float x) {
  return x > 20.f ? x : log1pf(expf(x));
}
__device__ __forceinline__ float silu_f(float x) {
  return x / (1.f + expf(-x));
}

// fp32 -> bf16 (n multiple of 2048)
__global__ __launch_bounds__(256) void f2bf_k(
    const float* __restrict__ in, __bf16* __restrict__ out, int n)
{
  const int i = (blockIdx.x * 256 + threadIdx.x) * 8;
  if (i >= n) return;
  const float4 a = *reinterpret_cast<const float4*>(in + i);
  const float4 b = *reinterpret_cast<const float4*>(in + i + 4);
  bf16_8 v;
  v[0]=(__bf16)a.x; v[1]=(__bf16)a.y; v[2]=(__bf16)a.z; v[3]=(__bf16)a.w;
  v[4]=(__bf16)b.x; v[5]=(__bf16)b.y; v[6]=(__bf16)b.z; v[7]=(__bf16)b.w;
  *reinterpret_cast<bf16_8*>(out + i) = v;
}

// ---- MFMA bf16 GEMM: C[M,N] = A[M,K](lda) @ W[N,K](ldw)^T ----
// flags: 1=accumulate, 2=softplus, 4=bias
__global__ __launch_bounds__(256) void gemm_mfma(
    const __bf16* __restrict__ A, int lda,
    const __bf16* __restrict__ W, int ldw,
    const float* __restrict__ bias, float* __restrict__ C, int ldc,
    int K, int flags)
{
  __shared__ __bf16 As[128 * 32];
  __shared__ __bf16 Ws[128 * 32];
  const int tid  = threadIdx.x;
  const int lane = tid & 63;
  const int w    = tid >> 6;
  const int wr   = w >> 1, wc = w & 1;
  const int row0 = blockIdx.y * 128, col0 = blockIdx.x * 128;

  f32x4 acc[4][4] = {};

  for (int k0 = 0; k0 < K; k0 += 32) {
    #pragma unroll
    for (int j = 0; j < 2; ++j) {
      const int inst = w * 2 + j;
      const int eo   = inst * 512 + lane * 8;
      const int r    = eo >> 5, k = eo & 31;
      __builtin_amdgcn_global_load_lds(
          (const __attribute__((address_space(1))) void*)(A + (size_t)(row0 + r) * lda + k0 + k),
          (__attribute__((address_space(3))) void*)(&As[inst * 512]), 16, 0, 0);
      __builtin_amdgcn_global_load_lds(
          (const __attribute__((address_space(1))) void*)(W + (size_t)(col0 + r) * ldw + k0 + k),
          (__attribute__((address_space(3))) void*)(&Ws[inst * 512]), 16, 0, 0);
    }
    __syncthreads();
    bf16_8 af[4], bfr[4];
    const int kk  = (lane >> 4) * 8;
    const int r16 = lane & 15;
    #pragma unroll
    for (int m = 0; m < 4; ++m)
      af[m] = *reinterpret_cast<const bf16_8*>(&As[(wr * 64 + m * 16 + r16) * 32 + kk]);
    #pragma unroll
    for (int n = 0; n < 4; ++n)
      bfr[n] = *reinterpret_cast<const bf16_8*>(&Ws[(wc * 64 + n * 16 + r16) * 32 + kk]);
    #pragma unroll
    for (int m = 0; m < 4; ++m)
      #pragma unroll
      for (int n = 0; n < 4; ++n)
        acc[m][n] = __builtin_amdgcn_mfma_f32_16x16x32_bf16(af[m], bfr[n], acc[m][n], 0, 0, 0);
    __syncthreads();
  }

  const int crow = (lane >> 4) * 4;
  const int ccol = lane & 15;
  #pragma unroll
  for (int m = 0; m < 4; ++m)
    #pragma unroll
    for (int n = 0; n < 4; ++n) {
      const int col = col0 + wc * 64 + n * 16 + ccol;
      const float bv = (flags & 4) ? bias[col] : 0.f;
      #pragma unroll
      for (int r = 0; r < 4; ++r) {
        const int row = row0 + wr * 64 + m * 16 + crow + r;
        float* cp = C + (size_t)row * ldc + col;
        float v = acc[m][n][r] + bv;
        if (flags & 2) v = softplus_f(v);
        if (flags & 1) v += *cp;
        *cp = v;
      }
    }
}

// split-K MFMA GEMM (lda=ldw=K)
__global__ __launch_bounds__(256) void gemm_mfma_sk(
    const __bf16* __restrict__ A, const __bf16* __restrict__ W,
    float* __restrict__ partials, int M, int N, int K, int Kc)
{
  __shared__ __bf16 As[128 * 32];
  __shared__ __bf16 Ws[128 * 32];
  const int tid  = threadIdx.x;
  const int lane = tid & 63;
  const int w    = tid >> 6;
  const int wr   = w >> 1, wc = w & 1;
  const int row0 = blockIdx.y * 128, col0 = blockIdx.x * 128;
  const int kbase = blockIdx.z * Kc;

  f32x4 acc[4][4] = {};

  for (int k0 = kbase; k0 < kbase + Kc; k0 += 32) {
    #pragma unroll
    for (int j = 0; j < 2; ++j) {
      const int inst = w * 2 + j;
      const int eo   = inst * 512 + lane * 8;
      const int r    = eo >> 5, k = eo & 31;
      __builtin_amdgcn_global_load_lds(
          (const __attribute__((address_space(1))) void*)(A + (size_t)(row0 + r) * K + k0 + k),
          (__attribute__((address_space(3))) void*)(&As[inst * 512]), 16, 0, 0);
      __builtin_amdgcn_global_load_lds(
          (const __attribute__((address_space(1))) void*)(W + (size_t)(col0 + r) * K + k0 + k),
          (__attribute__((address_space(3))) void*)(&Ws[inst * 512]), 16, 0, 0);
    }
    __syncthreads();
    bf16_8 af[4], bfr[4];
    const int kk  = (lane >> 4) * 8;
    const int r16 = lane & 15;
    #pragma unroll
    for (int m = 0; m < 4; ++m)
      af[m] = *reinterpret_cast<const bf16_8*>(&As[(wr * 64 + m * 16 + r16) * 32 + kk]);
    #pragma unroll
    for (int n = 0; n < 4; ++n)
      bfr[n] = *reinterpret_cast<const bf16_8*>(&Ws[(wc * 64 + n * 16 + r16) * 32 + kk]);
    #pragma unroll
    for (int m = 0; m < 4; ++m)
      #pragma unroll
      for (int n = 0; n < 4; ++n)
        acc[m][n] = __builtin_amdgcn_mfma_f32_16x16x32_bf16(af[m], bfr[n], acc[m][n], 0, 0, 0);
    __syncthreads();
  }

  float* base = partials + (size_t)blockIdx.z * M * N;
  const int crow = (lane >> 4) * 4;
  const int ccol = lane & 15;
  #pragma unroll
  for (int m = 0; m < 4; ++m)
    #pragma unroll
    for (int n = 0; n < 4; ++n) {
      const int col = col0 + wc * 64 + n * 16 + ccol;
      #pragma unroll
      for (int r = 0; r < 4; ++r) {
        const int row = row0 + wr * 64 + m * 16 + crow + r;
        base[(size_t)row * N + col] = acc[m][n][r];
      }
    }
}

// reduce ZSPL partials -> C; flags: 1=accumulate into C, 4=bias (per column)
__global__ __launch_bounds__(256) void mfma_sk_reduce(
    const float* __restrict__ partials, const float* __restrict__ bias,
    float* __restrict__ C, int elems, int ncols, int flags)
{
  const int i = (blockIdx.x * 256 + threadIdx.x) * 4;
  if (i >= elems) return;
  float4 s = *reinterpret_cast<const float4*>(partials + i);
  #pragma unroll
  for (int z = 1; z < ZSPL; ++z) {
    const float4 p = *reinterpret_cast<const float4*>(partials + (size_t)z * elems + i);
    s.x += p.x; s.y += p.y; s.z += p.z; s.w += p.w;
  }
  if (flags & 4) {
    const float4 bv = *reinterpret_cast<const float4*>(bias + (i % ncols));
    s.x += bv.x; s.y += bv.y; s.z += bv.z; s.w += bv.w;
  }
  if (flags & 1) {
    const float4 ov = *reinterpret_cast<const float4*>(C + i);
    s.x += ov.x; s.y += ov.y; s.z += ov.z; s.w += ov.w;
  }
  *reinterpret_cast<float4*>(C + i) = s;
}

// split-K fp32 GEMM (xproj)
__global__ __launch_bounds__(256) void gemm_bt_sk(
    const float* __restrict__ A, int lda,
    const float* __restrict__ W, int ldw,
    float* __restrict__ partials, int ldc,
    int M, int N, int K)
{
  __shared__ float As[16][65];
  __shared__ float Ws[16][65];
  const int tid = threadIdx.x;
  const int row0 = blockIdx.y * 64, col0 = blockIdx.x * 64;
  const int Kc = K / KSPL;
  const int kbase = blockIdx.z * Kc;
  const int tx = tid & 15, ty = tid >> 4;
  const int lm = tid >> 2, lk = (tid & 3) << 2;
  float acc[4][4] = {};
  for (int k0 = kbase; k0 < kbase + Kc; k0 += 16) {
    float4 av = *reinterpret_cast<const float4*>(A + (size_t)(row0 + lm) * lda + k0 + lk);
    float4 wv = *reinterpret_cast<const float4*>(W + (size_t)(col0 + lm) * ldw + k0 + lk);
    __syncthreads();
    As[lk+0][lm]=av.x; As[lk+1][lm]=av.y; As[lk+2][lm]=av.z; As[lk+3][lm]=av.w;
    Ws[lk+0][lm]=wv.x; Ws[lk+1][lm]=wv.y; Ws[lk+2][lm]=wv.z; Ws[lk+3][lm]=wv.w;
    __syncthreads();
    #pragma unroll
    for (int k = 0; k < 16; ++k) {
      float a0 = As[k][ty*4+0], a1 = As[k][ty*4+1], a2 = As[k][ty*4+2], a3 = As[k][ty*4+3];
      float b0 = Ws[k][tx*4+0], b1 = Ws[k][tx*4+1], b2 = Ws[k][tx*4+2], b3 = Ws[k][tx*4+3];
      acc[0][0] += a0*b0; acc[0][1] += a0*b1; acc[0][2] += a0*b2; acc[0][3] += a0*b3;
      acc[1][0] += a1*b0; acc[1][1] += a1*b1; acc[1][2] += a1*b2; acc[1][3] += a1*b3;
      acc[2][0] += a2*b0; acc[2][1] += a2*b1; acc[2][2] += a2*b2; acc[2][3] += a2*b3;
      acc[3][0] += a3*b0; acc[3][1] += a3*b1; acc[3][2] += a3*b2; acc[3][3] += a3*b3;
    }
  }
  float* base = partials + (size_t)blockIdx.z * M * ldc;
  #pragma unroll
  for (int i = 0; i < 4; ++i) {
    const int r = row0 + ty*4 + i;
    float4 v = make_float4(acc[i][0], acc[i][1], acc[i][2], acc[i][3]);
    *reinterpret_cast<float4*>(base + (size_t)r * ldc + col0 + tx*4) = v;
  }
}

// reduce KSPL partials -> C (fp32) and Cbf (bf16 copy, feeds dt MFMA GEMM)
__global__ __launch_bounds__(256) void sk_reduce_k(
    const float* __restrict__ partials, float* __restrict__ C,
    __bf16* __restrict__ Cbf, int elems)
{
  const int i = (blockIdx.x * 256 + threadIdx.x) * 4;
  if (i >= elems) return;
  float4 s = *reinterpret_cast<const float4*>(partials + i);
  #pragma unroll
  for (int z = 1; z < KSPL; ++z) {
    const float4 p = *reinterpret_cast<const float4*>(partials + (size_t)z * elems + i);
    s.x += p.x; s.y += p.y; s.z += p.z; s.w += p.w;
  }
  *reinterpret_cast<float4*>(C + i) = s;
  bf16_4 b;
  b[0]=(__bf16)s.x; b[1]=(__bf16)s.y; b[2]=(__bf16)s.z; b[3]=(__bf16)s.w;
  *reinterpret_cast<bf16_4*>(Cbf + i) = b;
}

// layernorm, fp32 out (final LN)
__global__ __launch_bounds__(256) void layernorm_k(
    const float* __restrict__ x, const float* __restrict__ g,
    const float* __restrict__ b, float* __restrict__ out)
{
  __shared__ float red[8];
  const int row = blockIdx.x;
  const int tid = threadIdx.x;
  const float* xr = x + (size_t)row * D_;
  float4 v = *reinterpret_cast<const float4*>(xr + tid * 4);
  float s = v.x + v.y + v.z + v.w;
  #pragma unroll
  for (int off = 32; off; off >>= 1) s += __shfl_down(s, off, 64);
  if ((tid & 63) == 0) red[tid >> 6] = s;
  __syncthreads();
  const float m = (red[0] + red[1] + red[2] + red[3]) * (1.f / D_);
  float dx0 = v.x - m, dx1 = v.y - m, dx2 = v.z - m, dx3 = v.w - m;
  float ss = dx0*dx0 + dx1*dx1 + dx2*dx2 + dx3*dx3;
  #pragma unroll
  for (int off = 32; off; off >>= 1) ss += __shfl_down(ss, off, 64);
  if ((tid & 63) == 0) red[4 + (tid >> 6)] = ss;
  __syncthreads();
  const float var = (red[4] + red[5] + red[6] + red[7]) * (1.f / D_);
  const float rs = rsqrtf(var + 1e-5f);
  const int c = tid * 4;
  const float4 gv = *reinterpret_cast<const float4*>(g + c);
  const float4 bv = *reinterpret_cast<const float4*>(b + c);
  float4 o;
  o.x = dx0 * rs * gv.x + bv.x;
  o.y = dx1 * rs * gv.y + bv.y;
  o.z = dx2 * rs * gv.z + bv.z;
  o.w = dx3 * rs * gv.w + bv.w;
  *reinterpret_cast<float4*>(out + (size_t)row * D_ + c) = o;
}

// layernorm with bf16 out (feeds MFMA GEMM)
__global__ __launch_bounds__(256) void layernorm_bf_k(
    const float* __restrict__ x, const float* __restrict__ g,
    const float* __restrict__ b, __bf16* __restrict__ out)
{
  __shared__ float red[8];
  const int row = blockIdx.x;
  const int tid = threadIdx.x;
  const float* xr = x + (size_t)row * D_;
  float4 v = *reinterpret_cast<const float4*>(xr + tid * 4);
  float s = v.x + v.y + v.z + v.w;
  #pragma unroll
  for (int off = 32; off; off >>= 1) s += __shfl_down(s, off, 64);
  if ((tid & 63) == 0) red[tid >> 6] = s;
  __syncthreads();
  const float m = (red[0] + red[1] + red[2] + red[3]) * (1.f / D_);
  float dx0 = v.x - m, dx1 = v.y - m, dx2 = v.z - m, dx3 = v.w - m;
  float ss = dx0*dx0 + dx1*dx1 + dx2*dx2 + dx3*dx3;
  #pragma unroll
  for (int off = 32; off; off >>= 1) ss += __shfl_down(ss, off, 64);
  if ((tid & 63) == 0) red[4 + (tid >> 6)] = ss;
  __syncthreads();
  const float var = (red[4] + red[5] + red[6] + red[7]) * (1.f / D_);
  const float rs = rsqrtf(var + 1e-5f);
  const int c = tid * 4;
  const float4 gv = *reinterpret_cast<const float4*>(g + c);
  const float4 bv = *reinterpret_cast<const float4*>(b + c);
  bf16_4 o;
  o[0] = (__bf16)(dx0 * rs * gv.x + bv.x);
  o[1] = (__bf16)(dx1 * rs * gv.y + bv.y);
  o[2] = (__bf16)(dx2 * rs * gv.z + bv.z);
  o[3] = (__bf16)(dx3 * rs * gv.w + bv.w);
  *reinterpret_cast<bf16_4*>(out + (size_t)row * D_ + c) = o;
}

// depthwise causal conv K=4 + bias + silu; 8 timesteps per thread
__global__ __launch_bounds__(256) void conv_silu_k(
    const float* __restrict__ xz, const float* __restrict__ cw,
    const float* __restrict__ cb, float* __restrict__ u)
{
  const int e = blockIdx.x * 256 + threadIdx.x;
  const int t0 = blockIdx.y * 8;
  const float w0 = cw[e*4+0], w1 = cw[e*4+1], w2 = cw[e*4+2], w3 = cw[e*4+3];
  const float b = cb[e];
  float x0 = (t0 >= 3) ? xz[(size_t)(t0-3)*(2*ED_)+e] : 0.f;
  float x1 = (t0 >= 2) ? xz[(size_t)(t0-2)*(2*ED_)+e] : 0.f;
  float x2 = (t0 >= 1) ? xz[(size_t)(t0-1)*(2*ED_)+e] : 0.f;
  #pragma unroll
  for (int j = 0; j < 8; ++j) {
    const float x3 = xz[(size_t)(t0+j)*(2*ED_)+e];
    const float acc = b + w0*x0 + w1*x1 + w2*x2 + w3*x3;
    u[(size_t)(t0+j)*ED_+e] = silu_f(acc);
    x0 = x1; x1 = x2; x2 = x3;
  }
}

// ---- chunked selective scan ----
__global__ __launch_bounds__(256) void scan_phase1(
    const float* __restrict__ delta, const float* __restrict__ u,
    const float* __restrict__ xdbl, const float* __restrict__ A_log,
    float* __restrict__ hend, float* __restrict__ Pend)
{
  const int tid = threadIdx.x;
  const int n = tid & 31;
  const int e = blockIdx.x * 8 + (tid >> 5);
  const int c = blockIdx.y;
  const float a = -expf(A_log[e * NST + n]);
  float h = 0.f, S = 0.f;
  const int t0 = c * CHUNK;
  #pragma unroll 8
  for (int t = t0; t < t0 + CHUNK; ++t) {
    const float sd = delta[(size_t)t * ED_ + e];
    const float uv = u[(size_t)t * ED_ + e];
    const float Bv = xdbl[(size_t)t * 128 + 64 + n];
    const float dA = __expf(sd * a);
    h = fmaf(dA, h, sd * uv * Bv);
    S += sd;
  }
  const int idx = c * (ED_ * NST) + blockIdx.x * 256 + tid;
  hend[idx] = h;
  Pend[idx] = __expf(a * S);
}

// phase 3: inline h_in combine + software-pipelined LDS-staged tiles.
// LDS ~22.5KB -> 7 blocks/CU.
__global__ __launch_bounds__(256, 7) void scan_phase3(
    const float* __restrict__ delta, const float* __restrict__ u,
    const float* __restrict__ xdbl, const float* __restrict__ A_log,
    const float* __restrict__ hend, const float* __restrict__ Pend,
    const float* __restrict__ Dp,
    const float* __restrict__ xz, __bf16* __restrict__ y)
{
  __shared__ float p_lds[8][16][33];      // 16896 B
  __shared__ float dl[16][8], ul[16][8], zl[16][8];  // 1536 B
  __shared__ float bc[16][64];            // 4096 B
  const int tid = threadIdx.x;
  const int n = tid & 31;
  const int c = tid >> 5;
  const int e0 = blockIdx.x * 8;
  const int e = e0 + c;
  const int ch = blockIdx.y;
  const float a = -expf(A_log[e * NST + n]);
  const float dp = Dp[e];

  // inline chunk combine (was scan_phase2): h_in for chunk ch
  float h = 0.f;
  {
    const int sidx = blockIdx.x * 256 + tid;
    for (int cc = 0; cc < ch; ++cc) {
      const int off = cc * (ED_ * NST) + sidx;
      h = fmaf(Pend[off], h, hend[off]);
    }
  }

  const int t0 = ch * CHUNK;
  const int r = n & 15, half = n >> 4;
  // staging roles
  const int s_t  = (tid & 127) >> 3;   // 0..15
  const int s_e  = tid & 7;            // 0..7
  const int b_t  = tid >> 4;           // 0..15
  const int b_c  = (tid & 15) * 4;     // 0..60

  // prologue: load tile 0 into registers
  float rg_a = 0.f, rg_z = 0.f;
  float4 rg_bc;
  {
    const int t = t0 + s_t;
    if (tid < 128) {
      rg_a = delta[(size_t)t * ED_ + e0 + s_e];
      rg_z = xz[(size_t)t * (2*ED_) + ED_ + e0 + s_e];
    } else {
      rg_a = u[(size_t)t * ED_ + e0 + s_e];
    }
    rg_bc = *reinterpret_cast<const float4*>(&xdbl[(size_t)(t0 + b_t) * 128 + 64 + b_c]);
  }

  for (int tb = 0; tb < CHUNK; tb += 16) {
    // write staged regs to LDS
    if (tid < 128) { dl[s_t][s_e] = rg_a; zl[s_t][s_e] = rg_z; }
    else          { ul[s_t][s_e] = rg_a; }
    *reinterpret_cast<float4*>(&bc[b_t][b_c]) = rg_bc;
    __syncthreads();
    // issue next tile's loads (overlap with compute below)
    if (tb + 16 < CHUNK) {
      const int t = t0 + tb + 16 + s_t;
      if (tid < 128) {
        rg_a = delta[(size_t)t * ED_ + e0 + s_e];
        rg_z = xz[(size_t)t * (2*ED_) + ED_ + e0 + s_e];
      } else {
        rg_a = u[(size_t)t * ED_ + e0 + s_e];
      }
      rg_bc = *reinterpret_cast<const float4*>(&xdbl[(size_t)(t0 + tb + 16 + b_t) * 128 + 64 + b_c]);
    }
    // 16 scan steps from LDS
    #pragma unroll
    for (int j = 0; j < 16; ++j) {
      const float sd = dl[j][c];
      const float uv = ul[j][c];
      const float Bv = bc[j][n];
      const float Cv = bc[j][32 + n];
      const float dA = __expf(sd * a);
      h = fmaf(dA, h, sd * uv * Bv);
      p_lds[c][j][n] = h * Cv;
    }
    __syncthreads();
    // deferred n-reduction: lane (r,half) sums half of row r, then shfl
    float s = 0.f;
    #pragma unroll
    for (int k = 0; k < 16; ++k) s += p_lds[c][r][half * 16 + k];
    s += __shfl_xor(s, 16, 64);
    if (half == 0) {
      const float uvt = ul[r][c];
      const float zv  = zl[r][c];
      y[(size_t)(t0 + tb + r) * ED_ + e] = (__bf16)((s + uvt * dp) * silu_f(zv));
    }
    __syncthreads();
  }
}

__global__ __launch_bounds__(256) void colmean_k(const float* __restrict__ hf, float* __restrict__ cm)
{
  const int d = blockIdx.x * 256 + threadIdx.x;
  float s = 0.f;
  for (int t = 0; t < L_; ++t) s += hf[(size_t)t * D_ + d];
  cm[d] = s * (1.f / L_);
}

__global__ __launch_bounds__(256) void state_k(
    const float* __restrict__ cm, const float* __restrict__ spw,
    const float* __restrict__ spb, float* __restrict__ out)
{
  __shared__ float red[4];
  const int nidx = blockIdx.x;
  const int tid = threadIdx.x;
  float s = 0.f;
  for (int d = tid; d < D_; d += 256) s += cm[d] * spw[(size_t)nidx * D_ + d];
  #pragma unroll
  for (int off = 32; off; off >>= 1) s += __shfl_down(s, off, 64);
  if ((tid & 63) == 0) red[tid >> 6] = s;
  __syncthreads();
  if (tid == 0) out[nidx] = red[0] + red[1] + red[2] + red[3] + spb[nidx];
}

extern "C" void kernel_launch(void* const* d_in, const int* in_sizes, int n_in,
                              void* d_out, int out_size, void* d_ws, size_t ws_size,
                              hipStream_t stream) {
  const float* x        = (const float*)d_in[0];
  const float* Wi       = (const float*)d_in[1];
  const float* bi       = (const float*)d_in[2];
  const float* ln_g     = (const float*)d_in[3];
  const float* ln_b     = (const float*)d_in[4];
  const float* in_w     = (const float*)d_in[5];
  const float* conv_w   = (const float*)d_in[6];
  const float* conv_b   = (const float*)d_in[7];
  const float* xproj_w  = (const float*)d_in[8];
  const float* dtproj_w = (const float*)d_in[9];
  const float* dtproj_b = (const float*)d_in[10];
  const float* A_log    = (const float*)d_in[11];
  const float* Dp       = (const float*)d_in[12];
  const float* out_w    = (const float*)d_in[13];
  const float* fn_g     = (const float*)d_in[14];
  const float* fn_b     = (const float*)d_in[15];
  const float* sp_w     = (const float*)d_in[16];
  const float* sp_b     = (const float*)d_in[17];
  float* out  = (float*)d_out;
  float* ws_f = (float*)d_ws;

  float* h_buf  = ws_f;                // 1048576
  float* xz     = ws_f + 1048576;      // 4194304
  float* u_buf  = ws_f + 5242880;      // 2097152
  float* xdbl   = ws_f + 7340032;      // 131072
  float* delta  = ws_f + 7471104;      // 2097152
  float* hend   = ws_f + 9568256;      // 524288
  float* pend   = ws_f + 10092544;     // 524288
  float* cmean  = ws_f + 10616832;     // 1024
  __bf16* nbf   = (__bf16*)(ws_f + 10617856);  // 1M bf16
  __bf16* ybf   = (__bf16*)(ws_f + 11142144);  // 2M bf16
  __bf16* wbf   = (__bf16*)(ws_f + 12190720);  // 8M bf16
  __bf16* xdblbf= (__bf16*)(ws_f + 16385024);  // 128K bf16
  __bf16* dtwbf = (__bf16*)(ws_f + 16450560);  // 128K bf16
  float* skpart = hend;                // xproj split-K partials (overlay)
  float* skmf   = u_buf;               // MFMA split-K partials (overlay)

  const dim3 blk(256);

  // h = x @ Wi^T + bi   (bf16 MFMA, split-K=4)
  f2bf_k<<<512, blk, 0, stream>>>(x, nbf, L_ * D_);
  f2bf_k<<<512, blk, 0, stream>>>(Wi, wbf, D_ * D_);
  gemm_mfma_sk<<<dim3(D_/128, L_/128, ZSPL), blk, 0, stream>>>(
      nbf, wbf, skmf, L_, D_, D_, D_/ZSPL);
  mfma_sk_reduce<<<dim3(L_*D_/4/256), blk, 0, stream>>>(
      skmf, bi, h_buf, L_*D_, D_, 4);

  for (int i = 0; i < NB_; ++i) {
    layernorm_bf_k<<<L_, blk, 0, stream>>>(h_buf, ln_g + i*D_, ln_b + i*D_, nbf);
    // xz = normed @ in_w^T
    f2bf_k<<<2048, blk, 0, stream>>>(in_w + (size_t)i*2*ED_*D_, wbf, 2*ED_*D_);
    gemm_mfma<<<dim3(2*ED_/128, L_/128), blk, 0, stream>>>(
        nbf, D_, wbf, D_, nullptr, xz, 2*ED_, D_, 0);
    conv_silu_k<<<dim3(ED_/256, L_/8), blk, 0, stream>>>(
        xz, conv_w + (size_t)i*ED_*KCONV, conv_b + (size_t)i*ED_, u_buf);
    // x_dbl = u @ xproj^T  (fp32 split-K over 8 chunks; emits fp32 + bf16)
    gemm_bt_sk<<<dim3(128/64, L_/64, KSPL), blk, 0, stream>>>(
        u_buf, ED_, xproj_w + (size_t)i*128*ED_, ED_, skpart, 128, L_, 128, ED_);
    sk_reduce_k<<<dim3(L_*128/4/256), blk, 0, stream>>>(skpart, xdbl, xdblbf, L_ * 128);
    // delta = softplus(dt @ dtproj^T + b)  (bf16 MFMA, K=64)
    f2bf_k<<<64, blk, 0, stream>>>(dtproj_w + (size_t)i*ED_*DTR_, dtwbf, ED_*DTR_);
    gemm_mfma<<<dim3(ED_/128, L_/128), blk, 0, stream>>>(
        xdblbf, 128, dtwbf, DTR_, dtproj_b + (size_t)i*ED_, delta, ED_, DTR_, 2 | 4);
    // chunked scan (phase2 folded into phase3)
    scan_phase1<<<dim3(ED_/8, NCH), blk, 0, stream>>>(
        delta, u_buf, xdbl, A_log + (size_t)i*ED_*NST, hend, pend);
    scan_phase3<<<dim3(ED_/8, NCH), blk, 0, stream>>>(
        delta, u_buf, xdbl, A_log + (size_t)i*ED_*NST, hend, pend,
        Dp + (size_t)i*ED_, xz, ybf);
    // h += y @ out_w^T   (bf16 MFMA, split-K=4)
    f2bf_k<<<1024, blk, 0, stream>>>(out_w + (size_t)i*D_*ED_, wbf, D_*ED_);
    gemm_mfma_sk<<<dim3(D_/128, L_/128, ZSPL), blk, 0, stream>>>(
        ybf, wbf, skmf, L_, D_, ED_, ED_/ZSPL);
    mfma_sk_reduce<<<dim3(L_*D_/4/256), blk, 0, stream>>>(
        skmf, nullptr, h_buf, L_*D_, D_, 1);
  }

  layernorm_k<<<L_, blk, 0, stream>>>(h_buf, fn_g, fn_b, out);
  colmean_k<<<D_/256, blk, 0, stream>>>(out, cmean);
  state_k<<<NST, blk, 0, stream>>>(cmean, sp_w, sp_b, out + (size_t)L_*D_);
}

// Round 9
// 712.944 us; speedup vs baseline: 1.2340x; 1.1069x over previous
//
#include <hip/hip_runtime.h>
#include <math.h>

#define D_    1024
#define ED_   2048
#define NST   32
#define KCONV 4
#define DTR_  64
#define L_    1024
#define NB_   4
#define NCH   8
#define CHUNK (L_ / NCH)
#define KSPL  8
#define ZSPL  4

typedef __bf16 bf16_8 __attribute__((ext_vector_type(8)));
typedef __bf16 bf16_4 __attribute__((ext_vector_type(4)));
typedef float  f32x4  __attribute__((ext_vector_type(4)));

__device__ __forceinline__ float softplus_f(float x) {
  return x > 20.f ? x : log1pf(expf(x));
}
__device__ __forceinline__ float silu_f(float x) {
  return x / (1.f + expf(-x));
}

// fp32 -> bf16 (n multiple of 2048)
__global__ __launch_bounds__(256) void f2bf_k(
    const float* __restrict__ in, __bf16* __restrict__ out, int n)
{
  const int i = (blockIdx.x * 256 + threadIdx.x) * 8;
  if (i >= n) return;
  const float4 a = *reinterpret_cast<const float4*>(in + i);
  const float4 b = *reinterpret_cast<const float4*>(in + i + 4);
  bf16_8 v;
  v[0]=(__bf16)a.x; v[1]=(__bf16)a.y; v[2]=(__bf16)a.z; v[3]=(__bf16)a.w;
  v[4]=(__bf16)b.x; v[5]=(__bf16)b.y; v[6]=(__bf16)b.z; v[7]=(__bf16)b.w;
  *reinterpret_cast<bf16_8*>(out + i) = v;
}

// ---- MFMA bf16 GEMM: C[M,N] = A[M,K](lda) @ W[N,K](ldw)^T ----
// flags: 1=accumulate, 2=softplus, 4=bias
__global__ __launch_bounds__(256) void gemm_mfma(
    const __bf16* __restrict__ A, int lda,
    const __bf16* __restrict__ W, int ldw,
    const float* __restrict__ bias, float* __restrict__ C, int ldc,
    int K, int flags)
{
  __shared__ __bf16 As[128 * 32];
  __shared__ __bf16 Ws[128 * 32];
  const int tid  = threadIdx.x;
  const int lane = tid & 63;
  const int w    = tid >> 6;
  const int wr   = w >> 1, wc = w & 1;
  const int row0 = blockIdx.y * 128, col0 = blockIdx.x * 128;

  f32x4 acc[4][4] = {};

  for (int k0 = 0; k0 < K; k0 += 32) {
    #pragma unroll
    for (int j = 0; j < 2; ++j) {
      const int inst = w * 2 + j;
      const int eo   = inst * 512 + lane * 8;
      const int r    = eo >> 5, k = eo & 31;
      __builtin_amdgcn_global_load_lds(
          (const __attribute__((address_space(1))) void*)(A + (size_t)(row0 + r) * lda + k0 + k),
          (__attribute__((address_space(3))) void*)(&As[inst * 512]), 16, 0, 0);
      __builtin_amdgcn_global_load_lds(
          (const __attribute__((address_space(1))) void*)(W + (size_t)(col0 + r) * ldw + k0 + k),
          (__attribute__((address_space(3))) void*)(&Ws[inst * 512]), 16, 0, 0);
    }
    __syncthreads();
    bf16_8 af[4], bfr[4];
    const int kk  = (lane >> 4) * 8;
    const int r16 = lane & 15;
    #pragma unroll
    for (int m = 0; m < 4; ++m)
      af[m] = *reinterpret_cast<const bf16_8*>(&As[(wr * 64 + m * 16 + r16) * 32 + kk]);
    #pragma unroll
    for (int n = 0; n < 4; ++n)
      bfr[n] = *reinterpret_cast<const bf16_8*>(&Ws[(wc * 64 + n * 16 + r16) * 32 + kk]);
    #pragma unroll
    for (int m = 0; m < 4; ++m)
      #pragma unroll
      for (int n = 0; n < 4; ++n)
        acc[m][n] = __builtin_amdgcn_mfma_f32_16x16x32_bf16(af[m], bfr[n], acc[m][n], 0, 0, 0);
    __syncthreads();
  }

  const int crow = (lane >> 4) * 4;
  const int ccol = lane & 15;
  #pragma unroll
  for (int m = 0; m < 4; ++m)
    #pragma unroll
    for (int n = 0; n < 4; ++n) {
      const int col = col0 + wc * 64 + n * 16 + ccol;
      const float bv = (flags & 4) ? bias[col] : 0.f;
      #pragma unroll
      for (int r = 0; r < 4; ++r) {
        const int row = row0 + wr * 64 + m * 16 + crow + r;
        float* cp = C + (size_t)row * ldc + col;
        float v = acc[m][n][r] + bv;
        if (flags & 2) v = softplus_f(v);
        if (flags & 1) v += *cp;
        *cp = v;
      }
    }
}

// split-K MFMA GEMM (lda=ldw=K)
__global__ __launch_bounds__(256) void gemm_mfma_sk(
    const __bf16* __restrict__ A, const __bf16* __restrict__ W,
    float* __restrict__ partials, int M, int N, int K, int Kc)
{
  __shared__ __bf16 As[128 * 32];
  __shared__ __bf16 Ws[128 * 32];
  const int tid  = threadIdx.x;
  const int lane = tid & 63;
  const int w    = tid >> 6;
  const int wr   = w >> 1, wc = w & 1;
  const int row0 = blockIdx.y * 128, col0 = blockIdx.x * 128;
  const int kbase = blockIdx.z * Kc;

  f32x4 acc[4][4] = {};

  for (int k0 = kbase; k0 < kbase + Kc; k0 += 32) {
    #pragma unroll
    for (int j = 0; j < 2; ++j) {
      const int inst = w * 2 + j;
      const int eo   = inst * 512 + lane * 8;
      const int r    = eo >> 5, k = eo & 31;
      __builtin_amdgcn_global_load_lds(
          (const __attribute__((address_space(1))) void*)(A + (size_t)(row0 + r) * K + k0 + k),
          (__attribute__((address_space(3))) void*)(&As[inst * 512]), 16, 0, 0);
      __builtin_amdgcn_global_load_lds(
          (const __attribute__((address_space(1))) void*)(W + (size_t)(col0 + r) * K + k0 + k),
          (__attribute__((address_space(3))) void*)(&Ws[inst * 512]), 16, 0, 0);
    }
    __syncthreads();
    bf16_8 af[4], bfr[4];
    const int kk  = (lane >> 4) * 8;
    const int r16 = lane & 15;
    #pragma unroll
    for (int m = 0; m < 4; ++m)
      af[m] = *reinterpret_cast<const bf16_8*>(&As[(wr * 64 + m * 16 + r16) * 32 + kk]);
    #pragma unroll
    for (int n = 0; n < 4; ++n)
      bfr[n] = *reinterpret_cast<const bf16_8*>(&Ws[(wc * 64 + n * 16 + r16) * 32 + kk]);
    #pragma unroll
    for (int m = 0; m < 4; ++m)
      #pragma unroll
      for (int n = 0; n < 4; ++n)
        acc[m][n] = __builtin_amdgcn_mfma_f32_16x16x32_bf16(af[m], bfr[n], acc[m][n], 0, 0, 0);
    __syncthreads();
  }

  float* base = partials + (size_t)blockIdx.z * M * N;
  const int crow = (lane >> 4) * 4;
  const int ccol = lane & 15;
  #pragma unroll
  for (int m = 0; m < 4; ++m)
    #pragma unroll
    for (int n = 0; n < 4; ++n) {
      const int col = col0 + wc * 64 + n * 16 + ccol;
      #pragma unroll
      for (int r = 0; r < 4; ++r) {
        const int row = row0 + wr * 64 + m * 16 + crow + r;
        base[(size_t)row * N + col] = acc[m][n][r];
      }
    }
}

// reduce ZSPL partials -> C; flags: 1=accumulate into C, 4=bias (per column)
__global__ __launch_bounds__(256) void mfma_sk_reduce(
    const float* __restrict__ partials, const float* __restrict__ bias,
    float* __restrict__ C, int elems, int ncols, int flags)
{
  const int i = (blockIdx.x * 256 + threadIdx.x) * 4;
  if (i >= elems) return;
  float4 s = *reinterpret_cast<const float4*>(partials + i);
  #pragma unroll
  for (int z = 1; z < ZSPL; ++z) {
    const float4 p = *reinterpret_cast<const float4*>(partials + (size_t)z * elems + i);
    s.x += p.x; s.y += p.y; s.z += p.z; s.w += p.w;
  }
  if (flags & 4) {
    const float4 bv = *reinterpret_cast<const float4*>(bias + (i % ncols));
    s.x += bv.x; s.y += bv.y; s.z += bv.z; s.w += bv.w;
  }
  if (flags & 1) {
    const float4 ov = *reinterpret_cast<const float4*>(C + i);
    s.x += ov.x; s.y += ov.y; s.z += ov.z; s.w += ov.w;
  }
  *reinterpret_cast<float4*>(C + i) = s;
}

// split-K fp32 GEMM (xproj)
__global__ __launch_bounds__(256) void gemm_bt_sk(
    const float* __restrict__ A, int lda,
    const float* __restrict__ W, int ldw,
    float* __restrict__ partials, int ldc,
    int M, int N, int K)
{
  __shared__ float As[16][65];
  __shared__ float Ws[16][65];
  const int tid = threadIdx.x;
  const int row0 = blockIdx.y * 64, col0 = blockIdx.x * 64;
  const int Kc = K / KSPL;
  const int kbase = blockIdx.z * Kc;
  const int tx = tid & 15, ty = tid >> 4;
  const int lm = tid >> 2, lk = (tid & 3) << 2;
  float acc[4][4] = {};
  for (int k0 = kbase; k0 < kbase + Kc; k0 += 16) {
    float4 av = *reinterpret_cast<const float4*>(A + (size_t)(row0 + lm) * lda + k0 + lk);
    float4 wv = *reinterpret_cast<const float4*>(W + (size_t)(col0 + lm) * ldw + k0 + lk);
    __syncthreads();
    As[lk+0][lm]=av.x; As[lk+1][lm]=av.y; As[lk+2][lm]=av.z; As[lk+3][lm]=av.w;
    Ws[lk+0][lm]=wv.x; Ws[lk+1][lm]=wv.y; Ws[lk+2][lm]=wv.z; Ws[lk+3][lm]=wv.w;
    __syncthreads();
    #pragma unroll
    for (int k = 0; k < 16; ++k) {
      float a0 = As[k][ty*4+0], a1 = As[k][ty*4+1], a2 = As[k][ty*4+2], a3 = As[k][ty*4+3];
      float b0 = Ws[k][tx*4+0], b1 = Ws[k][tx*4+1], b2 = Ws[k][tx*4+2], b3 = Ws[k][tx*4+3];
      acc[0][0] += a0*b0; acc[0][1] += a0*b1; acc[0][2] += a0*b2; acc[0][3] += a0*b3;
      acc[1][0] += a1*b0; acc[1][1] += a1*b1; acc[1][2] += a1*b2; acc[1][3] += a1*b3;
      acc[2][0] += a2*b0; acc[2][1] += a2*b1; acc[2][2] += a2*b2; acc[2][3] += a2*b3;
      acc[3][0] += a3*b0; acc[3][1] += a3*b1; acc[3][2] += a3*b2; acc[3][3] += a3*b3;
    }
  }
  float* base = partials + (size_t)blockIdx.z * M * ldc;
  #pragma unroll
  for (int i = 0; i < 4; ++i) {
    const int r = row0 + ty*4 + i;
    float4 v = make_float4(acc[i][0], acc[i][1], acc[i][2], acc[i][3]);
    *reinterpret_cast<float4*>(base + (size_t)r * ldc + col0 + tx*4) = v;
  }
}

// reduce KSPL partials -> C (fp32) and Cbf (bf16 copy, feeds dt MFMA GEMM)
__global__ __launch_bounds__(256) void sk_reduce_k(
    const float* __restrict__ partials, float* __restrict__ C,
    __bf16* __restrict__ Cbf, int elems)
{
  const int i = (blockIdx.x * 256 + threadIdx.x) * 4;
  if (i >= elems) return;
  float4 s = *reinterpret_cast<const float4*>(partials + i);
  #pragma unroll
  for (int z = 1; z < KSPL; ++z) {
    const float4 p = *reinterpret_cast<const float4*>(partials + (size_t)z * elems + i);
    s.x += p.x; s.y += p.y; s.z += p.z; s.w += p.w;
  }
  *reinterpret_cast<float4*>(C + i) = s;
  bf16_4 b;
  b[0]=(__bf16)s.x; b[1]=(__bf16)s.y; b[2]=(__bf16)s.z; b[3]=(__bf16)s.w;
  *reinterpret_cast<bf16_4*>(Cbf + i) = b;
}

// layernorm, fp32 out (final LN)
__global__ __launch_bounds__(256) void layernorm_k(
    const float* __restrict__ x, const float* __restrict__ g,
    const float* __restrict__ b, float* __restrict__ out)
{
  __shared__ float red[8];
  const int row = blockIdx.x;
  const int tid = threadIdx.x;
  const float* xr = x + (size_t)row * D_;
  float4 v = *reinterpret_cast<const float4*>(xr + tid * 4);
  float s = v.x + v.y + v.z + v.w;
  #pragma unroll
  for (int off = 32; off; off >>= 1) s += __shfl_down(s, off, 64);
  if ((tid & 63) == 0) red[tid >> 6] = s;
  __syncthreads();
  const float m = (red[0] + red[1] + red[2] + red[3]) * (1.f / D_);
  float dx0 = v.x - m, dx1 = v.y - m, dx2 = v.z - m, dx3 = v.w - m;
  float ss = dx0*dx0 + dx1*dx1 + dx2*dx2 + dx3*dx3;
  #pragma unroll
  for (int off = 32; off; off >>= 1) ss += __shfl_down(ss, off, 64);
  if ((tid & 63) == 0) red[4 + (tid >> 6)] = ss;
  __syncthreads();
  const float var = (red[4] + red[5] + red[6] + red[7]) * (1.f / D_);
  const float rs = rsqrtf(var + 1e-5f);
  const int c = tid * 4;
  const float4 gv = *reinterpret_cast<const float4*>(g + c);
  const float4 bv = *reinterpret_cast<const float4*>(b + c);
  float4 o;
  o.x = dx0 * rs * gv.x + bv.x;
  o.y = dx1 * rs * gv.y + bv.y;
  o.z = dx2 * rs * gv.z + bv.z;
  o.w = dx3 * rs * gv.w + bv.w;
  *reinterpret_cast<float4*>(out + (size_t)row * D_ + c) = o;
}

// layernorm with bf16 out (feeds MFMA GEMM)
__global__ __launch_bounds__(256) void layernorm_bf_k(
    const float* __restrict__ x, const float* __restrict__ g,
    const float* __restrict__ b, __bf16* __restrict__ out)
{
  __shared__ float red[8];
  const int row = blockIdx.x;
  const int tid = threadIdx.x;
  const float* xr = x + (size_t)row * D_;
  float4 v = *reinterpret_cast<const float4*>(xr + tid * 4);
  float s = v.x + v.y + v.z + v.w;
  #pragma unroll
  for (int off = 32; off; off >>= 1) s += __shfl_down(s, off, 64);
  if ((tid & 63) == 0) red[tid >> 6] = s;
  __syncthreads();
  const float m = (red[0] + red[1] + red[2] + red[3]) * (1.f / D_);
  float dx0 = v.x - m, dx1 = v.y - m, dx2 = v.z - m, dx3 = v.w - m;
  float ss = dx0*dx0 + dx1*dx1 + dx2*dx2 + dx3*dx3;
  #pragma unroll
  for (int off = 32; off; off >>= 1) ss += __shfl_down(ss, off, 64);
  if ((tid & 63) == 0) red[4 + (tid >> 6)] = ss;
  __syncthreads();
  const float var = (red[4] + red[5] + red[6] + red[7]) * (1.f / D_);
  const float rs = rsqrtf(var + 1e-5f);
  const int c = tid * 4;
  const float4 gv = *reinterpret_cast<const float4*>(g + c);
  const float4 bv = *reinterpret_cast<const float4*>(b + c);
  bf16_4 o;
  o[0] = (__bf16)(dx0 * rs * gv.x + bv.x);
  o[1] = (__bf16)(dx1 * rs * gv.y + bv.y);
  o[2] = (__bf16)(dx2 * rs * gv.z + bv.z);
  o[3] = (__bf16)(dx3 * rs * gv.w + bv.w);
  *reinterpret_cast<bf16_4*>(out + (size_t)row * D_ + c) = o;
}

// depthwise causal conv K=4 + bias + silu; 8 timesteps per thread
__global__ __launch_bounds__(256) void conv_silu_k(
    const float* __restrict__ xz, const float* __restrict__ cw,
    const float* __restrict__ cb, float* __restrict__ u)
{
  const int e = blockIdx.x * 256 + threadIdx.x;
  const int t0 = blockIdx.y * 8;
  const float w0 = cw[e*4+0], w1 = cw[e*4+1], w2 = cw[e*4+2], w3 = cw[e*4+3];
  const float b = cb[e];
  float x0 = (t0 >= 3) ? xz[(size_t)(t0-3)*(2*ED_)+e] : 0.f;
  float x1 = (t0 >= 2) ? xz[(size_t)(t0-2)*(2*ED_)+e] : 0.f;
  float x2 = (t0 >= 1) ? xz[(size_t)(t0-1)*(2*ED_)+e] : 0.f;
  #pragma unroll
  for (int j = 0; j < 8; ++j) {
    const float x3 = xz[(size_t)(t0+j)*(2*ED_)+e];
    const float acc = b + w0*x0 + w1*x1 + w2*x2 + w3*x3;
    u[(size_t)(t0+j)*ED_+e] = silu_f(acc);
    x0 = x1; x1 = x2; x2 = x3;
  }
}

// ---- chunked selective scan ----
// phase 1: LDS-staged pipelined per-chunk local scan; stores h_end, P_end.
__global__ __launch_bounds__(256) void scan_phase1(
    const float* __restrict__ delta, const float* __restrict__ u,
    const float* __restrict__ xdbl, const float* __restrict__ A_log,
    float* __restrict__ hend, float* __restrict__ Pend)
{
  __shared__ float dl[16][8], ul[16][8];
  __shared__ float bl[16][32];
  const int tid = threadIdx.x;
  const int n = tid & 31;
  const int c = tid >> 5;
  const int e0 = blockIdx.x * 8;
  const int e = e0 + c;
  const int ch = blockIdx.y;
  const float a = -expf(A_log[e * NST + n]);
  float h = 0.f, S = 0.f;
  const int t0 = ch * CHUNK;
  const int s_t = (tid & 127) >> 3, s_e = tid & 7;
  const int b_c = (tid & 7) * 4;

  float rg_a = 0.f;
  float4 rg_b;
  if (tid < 128) {
    rg_a = delta[(size_t)(t0 + s_t) * ED_ + e0 + s_e];
    rg_b = *reinterpret_cast<const float4*>(&xdbl[(size_t)(t0 + s_t) * 128 + 64 + b_c]);
  } else {
    rg_a = u[(size_t)(t0 + s_t) * ED_ + e0 + s_e];
  }

  for (int tb = 0; tb < CHUNK; tb += 16) {
    if (tid < 128) {
      dl[s_t][s_e] = rg_a;
      *reinterpret_cast<float4*>(&bl[s_t][b_c]) = rg_b;
    } else {
      ul[s_t][s_e] = rg_a;
    }
    __syncthreads();
    if (tb + 16 < CHUNK) {
      const int t = t0 + tb + 16 + s_t;
      if (tid < 128) {
        rg_a = delta[(size_t)t * ED_ + e0 + s_e];
        rg_b = *reinterpret_cast<const float4*>(&xdbl[(size_t)t * 128 + 64 + b_c]);
      } else {
        rg_a = u[(size_t)t * ED_ + e0 + s_e];
      }
    }
    #pragma unroll
    for (int j = 0; j < 16; ++j) {
      const float sd = dl[j][c];
      const float uv = ul[j][c];
      const float Bv = bl[j][n];
      h = fmaf(__expf(sd * a), h, sd * uv * Bv);
      S += sd;
    }
    __syncthreads();
  }
  const int idx = ch * (ED_ * NST) + blockIdx.x * 256 + tid;
  hend[idx] = h;
  Pend[idx] = __expf(a * S);
}

// phase 3: inline h_in combine + software-pipelined LDS-staged tiles.
__global__ __launch_bounds__(256, 7) void scan_phase3(
    const float* __restrict__ delta, const float* __restrict__ u,
    const float* __restrict__ xdbl, const float* __restrict__ A_log,
    const float* __restrict__ hend, const float* __restrict__ Pend,
    const float* __restrict__ Dp,
    const float* __restrict__ xz, __bf16* __restrict__ y)
{
  __shared__ float p_lds[8][16][33];      // 16896 B
  __shared__ float dl[16][8], ul[16][8], zl[16][8];  // 1536 B
  __shared__ float bc[16][64];            // 4096 B
  const int tid = threadIdx.x;
  const int n = tid & 31;
  const int c = tid >> 5;
  const int e0 = blockIdx.x * 8;
  const int e = e0 + c;
  const int ch = blockIdx.y;
  const float a = -expf(A_log[e * NST + n]);
  const float dp = Dp[e];

  float h = 0.f;
  {
    const int sidx = blockIdx.x * 256 + tid;
    for (int cc = 0; cc < ch; ++cc) {
      const int off = cc * (ED_ * NST) + sidx;
      h = fmaf(Pend[off], h, hend[off]);
    }
  }

  const int t0 = ch * CHUNK;
  const int r = n & 15, half = n >> 4;
  const int s_t  = (tid & 127) >> 3;
  const int s_e  = tid & 7;
  const int b_t  = tid >> 4;
  const int b_c  = (tid & 15) * 4;

  float rg_a = 0.f, rg_z = 0.f;
  float4 rg_bc;
  {
    const int t = t0 + s_t;
    if (tid < 128) {
      rg_a = delta[(size_t)t * ED_ + e0 + s_e];
      rg_z = xz[(size_t)t * (2*ED_) + ED_ + e0 + s_e];
    } else {
      rg_a = u[(size_t)t * ED_ + e0 + s_e];
    }
    rg_bc = *reinterpret_cast<const float4*>(&xdbl[(size_t)(t0 + b_t) * 128 + 64 + b_c]);
  }

  for (int tb = 0; tb < CHUNK; tb += 16) {
    if (tid < 128) { dl[s_t][s_e] = rg_a; zl[s_t][s_e] = rg_z; }
    else          { ul[s_t][s_e] = rg_a; }
    *reinterpret_cast<float4*>(&bc[b_t][b_c]) = rg_bc;
    __syncthreads();
    if (tb + 16 < CHUNK) {
      const int t = t0 + tb + 16 + s_t;
      if (tid < 128) {
        rg_a = delta[(size_t)t * ED_ + e0 + s_e];
        rg_z = xz[(size_t)t * (2*ED_) + ED_ + e0 + s_e];
      } else {
        rg_a = u[(size_t)t * ED_ + e0 + s_e];
      }
      rg_bc = *reinterpret_cast<const float4*>(&xdbl[(size_t)(t0 + tb + 16 + b_t) * 128 + 64 + b_c]);
    }
    #pragma unroll
    for (int j = 0; j < 16; ++j) {
      const float sd = dl[j][c];
      const float uv = ul[j][c];
      const float Bv = bc[j][n];
      const float Cv = bc[j][32 + n];
      const float dA = __expf(sd * a);
      h = fmaf(dA, h, sd * uv * Bv);
      p_lds[c][j][n] = h * Cv;
    }
    __syncthreads();
    float s = 0.f;
    #pragma unroll
    for (int k = 0; k < 16; ++k) s += p_lds[c][r][half * 16 + k];
    s += __shfl_xor(s, 16, 64);
    if (half == 0) {
      const float uvt = ul[r][c];
      const float zv  = zl[r][c];
      y[(size_t)(t0 + tb + r) * ED_ + e] = (__bf16)((s + uvt * dp) * silu_f(zv));
    }
    __syncthreads();
  }
}

// column-mean over rows, 2-phase: partials then finalize
__global__ __launch_bounds__(256) void colmean_part_k(
    const float* __restrict__ hf, float* __restrict__ part)
{
  const int d = blockIdx.x * 256 + threadIdx.x;
  const int tc = blockIdx.y;
  float s = 0.f;
  #pragma unroll 8
  for (int j = 0; j < 32; ++j) s += hf[(size_t)(tc * 32 + j) * D_ + d];
  part[tc * D_ + d] = s;
}

__global__ __launch_bounds__(256) void colmean_fin_k(
    const float* __restrict__ part, float* __restrict__ cm)
{
  const int d = blockIdx.x * 256 + threadIdx.x;
  float s = 0.f;
  #pragma unroll
  for (int c = 0; c < 32; ++c) s += part[c * D_ + d];
  cm[d] = s * (1.f / L_);
}

__global__ __launch_bounds__(256) void state_k(
    const float* __restrict__ cm, const float* __restrict__ spw,
    const float* __restrict__ spb, float* __restrict__ out)
{
  __shared__ float red[4];
  const int nidx = blockIdx.x;
  const int tid = threadIdx.x;
  float s = 0.f;
  for (int d = tid; d < D_; d += 256) s += cm[d] * spw[(size_t)nidx * D_ + d];
  #pragma unroll
  for (int off = 32; off; off >>= 1) s += __shfl_down(s, off, 64);
  if ((tid & 63) == 0) red[tid >> 6] = s;
  __syncthreads();
  if (tid == 0) out[nidx] = red[0] + red[1] + red[2] + red[3] + spb[nidx];
}

extern "C" void kernel_launch(void* const* d_in, const int* in_sizes, int n_in,
                              void* d_out, int out_size, void* d_ws, size_t ws_size,
                              hipStream_t stream) {
  const float* x        = (const float*)d_in[0];
  const float* Wi       = (const float*)d_in[1];
  const float* bi       = (const float*)d_in[2];
  const float* ln_g     = (const float*)d_in[3];
  const float* ln_b     = (const float*)d_in[4];
  const float* in_w     = (const float*)d_in[5];
  const float* conv_w   = (const float*)d_in[6];
  const float* conv_b   = (const float*)d_in[7];
  const float* xproj_w  = (const float*)d_in[8];
  const float* dtproj_w = (const float*)d_in[9];
  const float* dtproj_b = (const float*)d_in[10];
  const float* A_log    = (const float*)d_in[11];
  const float* Dp       = (const float*)d_in[12];
  const float* out_w    = (const float*)d_in[13];
  const float* fn_g     = (const float*)d_in[14];
  const float* fn_b     = (const float*)d_in[15];
  const float* sp_w     = (const float*)d_in[16];
  const float* sp_b     = (const float*)d_in[17];
  float* out  = (float*)d_out;
  float* ws_f = (float*)d_ws;

  float* h_buf  = ws_f;                // 1048576
  float* xz     = ws_f + 1048576;      // 4194304
  float* u_buf  = ws_f + 5242880;      // 2097152
  float* xdbl   = ws_f + 7340032;      // 131072
  float* delta  = ws_f + 7471104;      // 2097152
  float* hend   = ws_f + 9568256;      // 524288
  float* pend   = ws_f + 10092544;     // 524288
  float* cmean  = ws_f + 10616832;     // 1024
  __bf16* nbf   = (__bf16*)(ws_f + 10617856);  // 1M bf16
  __bf16* ybf   = (__bf16*)(ws_f + 11142144);  // 2M bf16
  __bf16* wbf   = (__bf16*)(ws_f + 12190720);  // 8M bf16
  __bf16* xdblbf= (__bf16*)(ws_f + 16385024);  // 128K bf16
  __bf16* dtwbf = (__bf16*)(ws_f + 16450560);  // 128K bf16
  float* skpart = hend;                // xproj split-K partials (overlay)
  float* skmf   = u_buf;               // MFMA split-K partials (overlay)
  float* cmpart = hend;                // colmean partials (overlay, 32*1024)

  const dim3 blk(256);

  // h = x @ Wi^T + bi   (bf16 MFMA, split-K=4)
  f2bf_k<<<512, blk, 0, stream>>>(x, nbf, L_ * D_);
  f2bf_k<<<512, blk, 0, stream>>>(Wi, wbf, D_ * D_);
  gemm_mfma_sk<<<dim3(D_/128, L_/128, ZSPL), blk, 0, stream>>>(
      nbf, wbf, skmf, L_, D_, D_, D_/ZSPL);
  mfma_sk_reduce<<<dim3(L_*D_/4/256), blk, 0, stream>>>(
      skmf, bi, h_buf, L_*D_, D_, 4);

  for (int i = 0; i < NB_; ++i) {
    layernorm_bf_k<<<L_, blk, 0, stream>>>(h_buf, ln_g + i*D_, ln_b + i*D_, nbf);
    // xz = normed @ in_w^T
    f2bf_k<<<2048, blk, 0, stream>>>(in_w + (size_t)i*2*ED_*D_, wbf, 2*ED_*D_);
    gemm_mfma<<<dim3(2*ED_/128, L_/128), blk, 0, stream>>>(
        nbf, D_, wbf, D_, nullptr, xz, 2*ED_, D_, 0);
    conv_silu_k<<<dim3(ED_/256, L_/8), blk, 0, stream>>>(
        xz, conv_w + (size_t)i*ED_*KCONV, conv_b + (size_t)i*ED_, u_buf);
    // x_dbl = u @ xproj^T  (fp32 split-K over 8 chunks; emits fp32 + bf16)
    gemm_bt_sk<<<dim3(128/64, L_/64, KSPL), blk, 0, stream>>>(
        u_buf, ED_, xproj_w + (size_t)i*128*ED_, ED_, skpart, 128, L_, 128, ED_);
    sk_reduce_k<<<dim3(L_*128/4/256), blk, 0, stream>>>(skpart, xdbl, xdblbf, L_ * 128);
    // delta = softplus(dt @ dtproj^T + b)  (bf16 MFMA, K=64)
    f2bf_k<<<64, blk, 0, stream>>>(dtproj_w + (size_t)i*ED_*DTR_, dtwbf, ED_*DTR_);
    gemm_mfma<<<dim3(ED_/128, L_/128), blk, 0, stream>>>(
        xdblbf, 128, dtwbf, DTR_, dtproj_b + (size_t)i*ED_, delta, ED_, DTR_, 2 | 4);
    // chunked scan
    scan_phase1<<<dim3(ED_/8, NCH), blk, 0, stream>>>(
        delta, u_buf, xdbl, A_log + (size_t)i*ED_*NST, hend, pend);
    scan_phase3<<<dim3(ED_/8, NCH), blk, 0, stream>>>(
        delta, u_buf, xdbl, A_log + (size_t)i*ED_*NST, hend, pend,
        Dp + (size_t)i*ED_, xz, ybf);
    // h += y @ out_w^T   (bf16 MFMA, split-K=4)
    f2bf_k<<<1024, blk, 0, stream>>>(out_w + (size_t)i*D_*ED_, wbf, D_*ED_);
    gemm_mfma_sk<<<dim3(D_/128, L_/128, ZSPL), blk, 0, stream>>>(
        ybf, wbf, skmf, L_, D_, ED_, ED_/ZSPL);
    mfma_sk_reduce<<<dim3(L_*D_/4/256), blk, 0, stream>>>(
        skmf, nullptr, h_buf, L_*D_, D_, 1);
  }

  layernorm_k<<<L_, blk, 0, stream>>>(h_buf, fn_g, fn_b, out);
  colmean_part_k<<<dim3(D_/256, 32), blk, 0, stream>>>(out, cmpart);
  colmean_fin_k<<<D_/256, blk, 0, stream>>>(cmpart, cmean);
  state_k<<<NST, blk, 0, stream>>>(cmean, sp_w, sp_b, out + (size_t)L_*D_);
}

// Round 10
// 673.628 us; speedup vs baseline: 1.3060x; 1.0584x over previous
//
#include <hip/hip_runtime.h>
#include <math.h>

#define D_    1024
#define ED_   2048
#define NST   32
#define KCONV 4
#define DTR_  64
#define L_    1024
#define NB_   4
#define NCH   8
#define CHUNK (L_ / NCH)
#define ZSPL  4
#define XPZ   16

typedef __bf16 bf16_8 __attribute__((ext_vector_type(8)));
typedef __bf16 bf16_4 __attribute__((ext_vector_type(4)));
typedef float  f32x4  __attribute__((ext_vector_type(4)));

__device__ __forceinline__ float softplus_f(float x) {
  return x > 20.f ? x : log1pf(expf(x));
}
__device__ __forceinline__ float silu_f(float x) {
  return x / (1.f + expf(-x));
}

// fp32 -> bf16 (n multiple of 2048)
__global__ __launch_bounds__(256) void f2bf_k(
    const float* __restrict__ in, __bf16* __restrict__ out, int n)
{
  const int i = (blockIdx.x * 256 + threadIdx.x) * 8;
  if (i >= n) return;
  const float4 a = *reinterpret_cast<const float4*>(in + i);
  const float4 b = *reinterpret_cast<const float4*>(in + i + 4);
  bf16_8 v;
  v[0]=(__bf16)a.x; v[1]=(__bf16)a.y; v[2]=(__bf16)a.z; v[3]=(__bf16)a.w;
  v[4]=(__bf16)b.x; v[5]=(__bf16)b.y; v[6]=(__bf16)b.z; v[7]=(__bf16)b.w;
  *reinterpret_cast<bf16_8*>(out + i) = v;
}

// ---- MFMA bf16 GEMM: C[M,N] = A[M,K](lda) @ W[N,K](ldw)^T ----
// 128x128 tile, BK=64, XOR-swizzled LDS (unit ^= row&7; pre-swizzled global src).
// flags: 1=accumulate, 2=softplus, 4=bias
__global__ __launch_bounds__(256) void gemm_mfma(
    const __bf16* __restrict__ A, int lda,
    const __bf16* __restrict__ W, int ldw,
    const float* __restrict__ bias, float* __restrict__ C, int ldc,
    int K, int flags)
{
  __shared__ __bf16 As[128 * 64];
  __shared__ __bf16 Ws[128 * 64];
  const int tid  = threadIdx.x;
  const int lane = tid & 63;
  const int w    = tid >> 6;
  const int wr   = w >> 1, wc = w & 1;
  const int row0 = blockIdx.y * 128, col0 = blockIdx.x * 128;

  f32x4 acc[4][4] = {};

  for (int k0 = 0; k0 < K; k0 += 64) {
    #pragma unroll
    for (int j = 0; j < 4; ++j) {
      const int inst = w * 4 + j;                 // 0..15, wave-uniform
      const int row  = inst * 8 + (lane >> 3);    // LDS dest row (linear)
      const int lu   = (lane & 7) ^ (row & 7);    // swizzled logical unit
      __builtin_amdgcn_global_load_lds(
          (const __attribute__((address_space(1))) void*)(A + (size_t)(row0 + row) * lda + k0 + lu * 8),
          (__attribute__((address_space(3))) void*)(&As[inst * 512]), 16, 0, 0);
      __builtin_amdgcn_global_load_lds(
          (const __attribute__((address_space(1))) void*)(W + (size_t)(col0 + row) * ldw + k0 + lu * 8),
          (__attribute__((address_space(3))) void*)(&Ws[inst * 512]), 16, 0, 0);
    }
    __syncthreads();
    const int r16 = lane & 15;
    const int uq  = lane >> 4;
    #pragma unroll
    for (int ks = 0; ks < 2; ++ks) {
      bf16_8 af[4], bfr[4];
      #pragma unroll
      for (int m = 0; m < 4; ++m) {
        const int row = wr * 64 + m * 16 + r16;
        const int pu  = (ks * 4 + uq) ^ (row & 7);
        af[m] = *reinterpret_cast<const bf16_8*>(&As[row * 64 + pu * 8]);
      }
      #pragma unroll
      for (int n = 0; n < 4; ++n) {
        const int row = wc * 64 + n * 16 + r16;
        const int pu  = (ks * 4 + uq) ^ (row & 7);
        bfr[n] = *reinterpret_cast<const bf16_8*>(&Ws[row * 64 + pu * 8]);
      }
      #pragma unroll
      for (int m = 0; m < 4; ++m)
        #pragma unroll
        for (int n = 0; n < 4; ++n)
          acc[m][n] = __builtin_amdgcn_mfma_f32_16x16x32_bf16(af[m], bfr[n], acc[m][n], 0, 0, 0);
    }
    __syncthreads();
  }

  const int crow = (lane >> 4) * 4;
  const int ccol = lane & 15;
  #pragma unroll
  for (int m = 0; m < 4; ++m)
    #pragma unroll
    for (int n = 0; n < 4; ++n) {
      const int col = col0 + wc * 64 + n * 16 + ccol;
      const float bv = (flags & 4) ? bias[col] : 0.f;
      #pragma unroll
      for (int r = 0; r < 4; ++r) {
        const int row = row0 + wr * 64 + m * 16 + crow + r;
        float* cp = C + (size_t)row * ldc + col;
        float v = acc[m][n][r] + bv;
        if (flags & 2) v = softplus_f(v);
        if (flags & 1) v += *cp;
        *cp = v;
      }
    }
}

// split-K MFMA GEMM (lda=ldw=K), BK=64 swizzled; partials[z][M][N]
__global__ __launch_bounds__(256) void gemm_mfma_sk(
    const __bf16* __restrict__ A, const __bf16* __restrict__ W,
    float* __restrict__ partials, int M, int N, int K, int Kc)
{
  __shared__ __bf16 As[128 * 64];
  __shared__ __bf16 Ws[128 * 64];
  const int tid  = threadIdx.x;
  const int lane = tid & 63;
  const int w    = tid >> 6;
  const int wr   = w >> 1, wc = w & 1;
  const int row0 = blockIdx.y * 128, col0 = blockIdx.x * 128;
  const int kbase = blockIdx.z * Kc;

  f32x4 acc[4][4] = {};

  for (int k0 = kbase; k0 < kbase + Kc; k0 += 64) {
    #pragma unroll
    for (int j = 0; j < 4; ++j) {
      const int inst = w * 4 + j;
      const int row  = inst * 8 + (lane >> 3);
      const int lu   = (lane & 7) ^ (row & 7);
      __builtin_amdgcn_global_load_lds(
          (const __attribute__((address_space(1))) void*)(A + (size_t)(row0 + row) * K + k0 + lu * 8),
          (__attribute__((address_space(3))) void*)(&As[inst * 512]), 16, 0, 0);
      __builtin_amdgcn_global_load_lds(
          (const __attribute__((address_space(1))) void*)(W + (size_t)(col0 + row) * K + k0 + lu * 8),
          (__attribute__((address_space(3))) void*)(&Ws[inst * 512]), 16, 0, 0);
    }
    __syncthreads();
    const int r16 = lane & 15;
    const int uq  = lane >> 4;
    #pragma unroll
    for (int ks = 0; ks < 2; ++ks) {
      bf16_8 af[4], bfr[4];
      #pragma unroll
      for (int m = 0; m < 4; ++m) {
        const int row = wr * 64 + m * 16 + r16;
        const int pu  = (ks * 4 + uq) ^ (row & 7);
        af[m] = *reinterpret_cast<const bf16_8*>(&As[row * 64 + pu * 8]);
      }
      #pragma unroll
      for (int n = 0; n < 4; ++n) {
        const int row = wc * 64 + n * 16 + r16;
        const int pu  = (ks * 4 + uq) ^ (row & 7);
        bfr[n] = *reinterpret_cast<const bf16_8*>(&Ws[row * 64 + pu * 8]);
      }
      #pragma unroll
      for (int m = 0; m < 4; ++m)
        #pragma unroll
        for (int n = 0; n < 4; ++n)
          acc[m][n] = __builtin_amdgcn_mfma_f32_16x16x32_bf16(af[m], bfr[n], acc[m][n], 0, 0, 0);
    }
    __syncthreads();
  }

  float* base = partials + (size_t)blockIdx.z * M * N;
  const int crow = (lane >> 4) * 4;
  const int ccol = lane & 15;
  #pragma unroll
  for (int m = 0; m < 4; ++m)
    #pragma unroll
    for (int n = 0; n < 4; ++n) {
      const int col = col0 + wc * 64 + n * 16 + ccol;
      #pragma unroll
      for (int r = 0; r < 4; ++r) {
        const int row = row0 + wr * 64 + m * 16 + crow + r;
        base[(size_t)row * N + col] = acc[m][n][r];
      }
    }
}

// reduce nz partials -> C; flags: 1=acc into C, 4=bias(per col), 8=emit bf16 copy
__global__ __launch_bounds__(256) void mfma_sk_reduce(
    const float* __restrict__ partials, const float* __restrict__ bias,
    float* __restrict__ C, __bf16* __restrict__ Cbf,
    int elems, int ncols, int nz, int flags)
{
  const int i = (blockIdx.x * 256 + threadIdx.x) * 4;
  if (i >= elems) return;
  float4 s = *reinterpret_cast<const float4*>(partials + i);
  for (int z = 1; z < nz; ++z) {
    const float4 p = *reinterpret_cast<const float4*>(partials + (size_t)z * elems + i);
    s.x += p.x; s.y += p.y; s.z += p.z; s.w += p.w;
  }
  if (flags & 4) {
    const float4 bv = *reinterpret_cast<const float4*>(bias + (i % ncols));
    s.x += bv.x; s.y += bv.y; s.z += bv.z; s.w += bv.w;
  }
  if (flags & 1) {
    const float4 ov = *reinterpret_cast<const float4*>(C + i);
    s.x += ov.x; s.y += ov.y; s.z += ov.z; s.w += ov.w;
  }
  *reinterpret_cast<float4*>(C + i) = s;
  if (flags & 8) {
    bf16_4 b;
    b[0]=(__bf16)s.x; b[1]=(__bf16)s.y; b[2]=(__bf16)s.z; b[3]=(__bf16)s.w;
    *reinterpret_cast<bf16_4*>(Cbf + i) = b;
  }
}

// layernorm, fp32 out (final LN)
__global__ __launch_bounds__(256) void layernorm_k(
    const float* __restrict__ x, const float* __restrict__ g,
    const float* __restrict__ b, float* __restrict__ out)
{
  __shared__ float red[8];
  const int row = blockIdx.x;
  const int tid = threadIdx.x;
  const float* xr = x + (size_t)row * D_;
  float4 v = *reinterpret_cast<const float4*>(xr + tid * 4);
  float s = v.x + v.y + v.z + v.w;
  #pragma unroll
  for (int off = 32; off; off >>= 1) s += __shfl_down(s, off, 64);
  if ((tid & 63) == 0) red[tid >> 6] = s;
  __syncthreads();
  const float m = (red[0] + red[1] + red[2] + red[3]) * (1.f / D_);
  float dx0 = v.x - m, dx1 = v.y - m, dx2 = v.z - m, dx3 = v.w - m;
  float ss = dx0*dx0 + dx1*dx1 + dx2*dx2 + dx3*dx3;
  #pragma unroll
  for (int off = 32; off; off >>= 1) ss += __shfl_down(ss, off, 64);
  if ((tid & 63) == 0) red[4 + (tid >> 6)] = ss;
  __syncthreads();
  const float var = (red[4] + red[5] + red[6] + red[7]) * (1.f / D_);
  const float rs = rsqrtf(var + 1e-5f);
  const int c = tid * 4;
  const float4 gv = *reinterpret_cast<const float4*>(g + c);
  const float4 bv = *reinterpret_cast<const float4*>(b + c);
  float4 o;
  o.x = dx0 * rs * gv.x + bv.x;
  o.y = dx1 * rs * gv.y + bv.y;
  o.z = dx2 * rs * gv.z + bv.z;
  o.w = dx3 * rs * gv.w + bv.w;
  *reinterpret_cast<float4*>(out + (size_t)row * D_ + c) = o;
}

// layernorm with bf16 out
__global__ __launch_bounds__(256) void layernorm_bf_k(
    const float* __restrict__ x, const float* __restrict__ g,
    const float* __restrict__ b, __bf16* __restrict__ out)
{
  __shared__ float red[8];
  const int row = blockIdx.x;
  const int tid = threadIdx.x;
  const float* xr = x + (size_t)row * D_;
  float4 v = *reinterpret_cast<const float4*>(xr + tid * 4);
  float s = v.x + v.y + v.z + v.w;
  #pragma unroll
  for (int off = 32; off; off >>= 1) s += __shfl_down(s, off, 64);
  if ((tid & 63) == 0) red[tid >> 6] = s;
  __syncthreads();
  const float m = (red[0] + red[1] + red[2] + red[3]) * (1.f / D_);
  float dx0 = v.x - m, dx1 = v.y - m, dx2 = v.z - m, dx3 = v.w - m;
  float ss = dx0*dx0 + dx1*dx1 + dx2*dx2 + dx3*dx3;
  #pragma unroll
  for (int off = 32; off; off >>= 1) ss += __shfl_down(ss, off, 64);
  if ((tid & 63) == 0) red[4 + (tid >> 6)] = ss;
  __syncthreads();
  const float var = (red[4] + red[5] + red[6] + red[7]) * (1.f / D_);
  const float rs = rsqrtf(var + 1e-5f);
  const int c = tid * 4;
  const float4 gv = *reinterpret_cast<const float4*>(g + c);
  const float4 bv = *reinterpret_cast<const float4*>(b + c);
  bf16_4 o;
  o[0] = (__bf16)(dx0 * rs * gv.x + bv.x);
  o[1] = (__bf16)(dx1 * rs * gv.y + bv.y);
  o[2] = (__bf16)(dx2 * rs * gv.z + bv.z);
  o[3] = (__bf16)(dx3 * rs * gv.w + bv.w);
  *reinterpret_cast<bf16_4*>(out + (size_t)row * D_ + c) = o;
}

// depthwise causal conv K=4 + bias + silu; 8 timesteps/thread; fp32 + bf16 out
__global__ __launch_bounds__(256) void conv_silu_k(
    const float* __restrict__ xz, const float* __restrict__ cw,
    const float* __restrict__ cb, float* __restrict__ u, __bf16* __restrict__ ub)
{
  const int e = blockIdx.x * 256 + threadIdx.x;
  const int t0 = blockIdx.y * 8;
  const float w0 = cw[e*4+0], w1 = cw[e*4+1], w2 = cw[e*4+2], w3 = cw[e*4+3];
  const float b = cb[e];
  float x0 = (t0 >= 3) ? xz[(size_t)(t0-3)*(2*ED_)+e] : 0.f;
  float x1 = (t0 >= 2) ? xz[(size_t)(t0-2)*(2*ED_)+e] : 0.f;
  float x2 = (t0 >= 1) ? xz[(size_t)(t0-1)*(2*ED_)+e] : 0.f;
  #pragma unroll
  for (int j = 0; j < 8; ++j) {
    const float x3 = xz[(size_t)(t0+j)*(2*ED_)+e];
    const float uv = silu_f(b + w0*x0 + w1*x1 + w2*x2 + w3*x3);
    u[(size_t)(t0+j)*ED_+e] = uv;
    ub[(size_t)(t0+j)*ED_+e] = (__bf16)uv;
    x0 = x1; x1 = x2; x2 = x3;
  }
}

// ---- chunked selective scan ----
__global__ __launch_bounds__(256) void scan_phase1(
    const float* __restrict__ delta, const float* __restrict__ u,
    const float* __restrict__ xdbl, const float* __restrict__ A_log,
    float* __restrict__ hend, float* __restrict__ Pend)
{
  __shared__ float dl[16][8], ul[16][8];
  __shared__ float bl[16][32];
  const int tid = threadIdx.x;
  const int n = tid & 31;
  const int c = tid >> 5;
  const int e0 = blockIdx.x * 8;
  const int e = e0 + c;
  const int ch = blockIdx.y;
  const float a = -expf(A_log[e * NST + n]);
  float h = 0.f, S = 0.f;
  const int t0 = ch * CHUNK;
  const int s_t = (tid & 127) >> 3, s_e = tid & 7;
  const int b_c = (tid & 7) * 4;

  float rg_a = 0.f;
  float4 rg_b;
  if (tid < 128) {
    rg_a = delta[(size_t)(t0 + s_t) * ED_ + e0 + s_e];
    rg_b = *reinterpret_cast<const float4*>(&xdbl[(size_t)(t0 + s_t) * 128 + 64 + b_c]);
  } else {
    rg_a = u[(size_t)(t0 + s_t) * ED_ + e0 + s_e];
  }

  for (int tb = 0; tb < CHUNK; tb += 16) {
    if (tid < 128) {
      dl[s_t][s_e] = rg_a;
      *reinterpret_cast<float4*>(&bl[s_t][b_c]) = rg_b;
    } else {
      ul[s_t][s_e] = rg_a;
    }
    __syncthreads();
    if (tb + 16 < CHUNK) {
      const int t = t0 + tb + 16 + s_t;
      if (tid < 128) {
        rg_a = delta[(size_t)t * ED_ + e0 + s_e];
        rg_b = *reinterpret_cast<const float4*>(&xdbl[(size_t)t * 128 + 64 + b_c]);
      } else {
        rg_a = u[(size_t)t * ED_ + e0 + s_e];
      }
    }
    #pragma unroll
    for (int j = 0; j < 16; ++j) {
      const float sd = dl[j][c];
      const float uv = ul[j][c];
      const float Bv = bl[j][n];
      h = fmaf(__expf(sd * a), h, sd * uv * Bv);
      S += sd;
    }
    __syncthreads();
  }
  const int idx = ch * (ED_ * NST) + blockIdx.x * 256 + tid;
  hend[idx] = h;
  Pend[idx] = __expf(a * S);
}

// phase 3: inline h_in combine + software-pipelined LDS-staged tiles.
__global__ __launch_bounds__(256, 7) void scan_phase3(
    const float* __restrict__ delta, const float* __restrict__ u,
    const float* __restrict__ xdbl, const float* __restrict__ A_log,
    const float* __restrict__ hend, const float* __restrict__ Pend,
    const float* __restrict__ Dp,
    const float* __restrict__ xz, __bf16* __restrict__ y)
{
  __shared__ float p_lds[8][16][33];
  __shared__ float dl[16][8], ul[16][8], zl[16][8];
  __shared__ float bc[16][64];
  const int tid = threadIdx.x;
  const int n = tid & 31;
  const int c = tid >> 5;
  const int e0 = blockIdx.x * 8;
  const int e = e0 + c;
  const int ch = blockIdx.y;
  const float a = -expf(A_log[e * NST + n]);
  const float dp = Dp[e];

  float h = 0.f;
  {
    const int sidx = blockIdx.x * 256 + tid;
    for (int cc = 0; cc < ch; ++cc) {
      const int off = cc * (ED_ * NST) + sidx;
      h = fmaf(Pend[off], h, hend[off]);
    }
  }

  const int t0 = ch * CHUNK;
  const int r = n & 15, half = n >> 4;
  const int s_t  = (tid & 127) >> 3;
  const int s_e  = tid & 7;
  const int b_t  = tid >> 4;
  const int b_c  = (tid & 15) * 4;

  float rg_a = 0.f, rg_z = 0.f;
  float4 rg_bc;
  {
    const int t = t0 + s_t;
    if (tid < 128) {
      rg_a = delta[(size_t)t * ED_ + e0 + s_e];
      rg_z = xz[(size_t)t * (2*ED_) + ED_ + e0 + s_e];
    } else {
      rg_a = u[(size_t)t * ED_ + e0 + s_e];
    }
    rg_bc = *reinterpret_cast<const float4*>(&xdbl[(size_t)(t0 + b_t) * 128 + 64 + b_c]);
  }

  for (int tb = 0; tb < CHUNK; tb += 16) {
    if (tid < 128) { dl[s_t][s_e] = rg_a; zl[s_t][s_e] = rg_z; }
    else          { ul[s_t][s_e] = rg_a; }
    *reinterpret_cast<float4*>(&bc[b_t][b_c]) = rg_bc;
    __syncthreads();
    if (tb + 16 < CHUNK) {
      const int t = t0 + tb + 16 + s_t;
      if (tid < 128) {
        rg_a = delta[(size_t)t * ED_ + e0 + s_e];
        rg_z = xz[(size_t)t * (2*ED_) + ED_ + e0 + s_e];
      } else {
        rg_a = u[(size_t)t * ED_ + e0 + s_e];
      }
      rg_bc = *reinterpret_cast<const float4*>(&xdbl[(size_t)(t0 + tb + 16 + b_t) * 128 + 64 + b_c]);
    }
    #pragma unroll
    for (int j = 0; j < 16; ++j) {
      const float sd = dl[j][c];
      const float uv = ul[j][c];
      const float Bv = bc[j][n];
      const float Cv = bc[j][32 + n];
      const float dA = __expf(sd * a);
      h = fmaf(dA, h, sd * uv * Bv);
      p_lds[c][j][n] = h * Cv;
    }
    __syncthreads();
    float s = 0.f;
    #pragma unroll
    for (int k = 0; k < 16; ++k) s += p_lds[c][r][half * 16 + k];
    s += __shfl_xor(s, 16, 64);
    if (half == 0) {
      const float uvt = ul[r][c];
      const float zv  = zl[r][c];
      y[(size_t)(t0 + tb + r) * ED_ + e] = (__bf16)((s + uvt * dp) * silu_f(zv));
    }
    __syncthreads();
  }
}

// column-mean over rows, 2-phase
__global__ __launch_bounds__(256) void colmean_part_k(
    const float* __restrict__ hf, float* __restrict__ part)
{
  const int d = blockIdx.x * 256 + threadIdx.x;
  const int tc = blockIdx.y;
  float s = 0.f;
  #pragma unroll 8
  for (int j = 0; j < 32; ++j) s += hf[(size_t)(tc * 32 + j) * D_ + d];
  part[tc * D_ + d] = s;
}

__global__ __launch_bounds__(256) void colmean_fin_k(
    const float* __restrict__ part, float* __restrict__ cm)
{
  const int d = blockIdx.x * 256 + threadIdx.x;
  float s = 0.f;
  #pragma unroll
  for (int c = 0; c < 32; ++c) s += part[c * D_ + d];
  cm[d] = s * (1.f / L_);
}

__global__ __launch_bounds__(256) void state_k(
    const float* __restrict__ cm, const float* __restrict__ spw,
    const float* __restrict__ spb, float* __restrict__ out)
{
  __shared__ float red[4];
  const int nidx = blockIdx.x;
  const int tid = threadIdx.x;
  float s = 0.f;
  for (int d = tid; d < D_; d += 256) s += cm[d] * spw[(size_t)nidx * D_ + d];
  #pragma unroll
  for (int off = 32; off; off >>= 1) s += __shfl_down(s, off, 64);
  if ((tid & 63) == 0) red[tid >> 6] = s;
  __syncthreads();
  if (tid == 0) out[nidx] = red[0] + red[1] + red[2] + red[3] + spb[nidx];
}

extern "C" void kernel_launch(void* const* d_in, const int* in_sizes, int n_in,
                              void* d_out, int out_size, void* d_ws, size_t ws_size,
                              hipStream_t stream) {
  const float* x        = (const float*)d_in[0];
  const float* Wi       = (const float*)d_in[1];
  const float* bi       = (const float*)d_in[2];
  const float* ln_g     = (const float*)d_in[3];
  const float* ln_b     = (const float*)d_in[4];
  const float* in_w     = (const float*)d_in[5];
  const float* conv_w   = (const float*)d_in[6];
  const float* conv_b   = (const float*)d_in[7];
  const float* xproj_w  = (const float*)d_in[8];
  const float* dtproj_w = (const float*)d_in[9];
  const float* dtproj_b = (const float*)d_in[10];
  const float* A_log    = (const float*)d_in[11];
  const float* Dp       = (const float*)d_in[12];
  const float* out_w    = (const float*)d_in[13];
  const float* fn_g     = (const float*)d_in[14];
  const float* fn_b     = (const float*)d_in[15];
  const float* sp_w     = (const float*)d_in[16];
  const float* sp_b     = (const float*)d_in[17];
  float* out  = (float*)d_out;
  float* ws_f = (float*)d_ws;

  float* h_buf  = ws_f;                // 1048576
  float* xz     = ws_f + 1048576;      // 4194304
  float* u_buf  = ws_f + 5242880;      // 2097152
  float* xdbl   = ws_f + 7340032;      // 131072
  float* delta  = ws_f + 7471104;      // 2097152 (also xproj partials 16*131072)
  float* hend   = ws_f + 9568256;      // 524288
  float* pend   = ws_f + 10092544;     // 524288
  float* cmean  = ws_f + 10616832;     // 1024
  __bf16* nbf   = (__bf16*)(ws_f + 10617856);  // 1M bf16
  __bf16* ybf   = (__bf16*)(ws_f + 11142144);  // 2M bf16
  __bf16* wbf   = (__bf16*)(ws_f + 12190720);  // 8M bf16
  __bf16* xdblbf= (__bf16*)(ws_f + 16385024);  // 128K bf16
  __bf16* dtwbf = (__bf16*)(ws_f + 16450560);  // 128K bf16
  __bf16* ubf   = (__bf16*)(ws_f + 16516096);  // 2M bf16
  __bf16* xpbf  = (__bf16*)(ws_f + 17564672);  // 256K bf16
  float* skmf   = u_buf;               // MFMA split-K partials overlay (Wi/out)
  float* skxp   = delta;               // xproj split-K partials overlay
  float* cmpart = hend;                // colmean partials overlay

  const dim3 blk(256);

  // h = x @ Wi^T + bi   (bf16 MFMA, split-K=4)
  f2bf_k<<<512, blk, 0, stream>>>(x, nbf, L_ * D_);
  f2bf_k<<<512, blk, 0, stream>>>(Wi, wbf, D_ * D_);
  gemm_mfma_sk<<<dim3(D_/128, L_/128, ZSPL), blk, 0, stream>>>(
      nbf, wbf, skmf, L_, D_, D_, D_/ZSPL);
  mfma_sk_reduce<<<dim3(L_*D_/4/256), blk, 0, stream>>>(
      skmf, bi, h_buf, nullptr, L_*D_, D_, ZSPL, 4);

  for (int i = 0; i < NB_; ++i) {
    layernorm_bf_k<<<L_, blk, 0, stream>>>(h_buf, ln_g + i*D_, ln_b + i*D_, nbf);
    // xz = normed @ in_w^T
    f2bf_k<<<2048, blk, 0, stream>>>(in_w + (size_t)i*2*ED_*D_, wbf, 2*ED_*D_);
    gemm_mfma<<<dim3(2*ED_/128, L_/128), blk, 0, stream>>>(
        nbf, D_, wbf, D_, nullptr, xz, 2*ED_, D_, 0);
    conv_silu_k<<<dim3(ED_/256, L_/8), blk, 0, stream>>>(
        xz, conv_w + (size_t)i*ED_*KCONV, conv_b + (size_t)i*ED_, u_buf, ubf);
    // x_dbl = u @ xproj^T  (bf16 MFMA split-K=16)
    f2bf_k<<<128, blk, 0, stream>>>(xproj_w + (size_t)i*128*ED_, xpbf, 128*ED_);
    gemm_mfma_sk<<<dim3(1, L_/128, XPZ), blk, 0, stream>>>(
        ubf, xpbf, skxp, L_, 128, ED_, ED_/XPZ);
    mfma_sk_reduce<<<dim3(L_*128/4/256), blk, 0, stream>>>(
        skxp, nullptr, xdbl, xdblbf, L_*128, 128, XPZ, 8);
    // delta = softplus(dt @ dtproj^T + b)  (bf16 MFMA, K=64)
    f2bf_k<<<64, blk, 0, stream>>>(dtproj_w + (size_t)i*ED_*DTR_, dtwbf, ED_*DTR_);
    gemm_mfma<<<dim3(ED_/128, L_/128), blk, 0, stream>>>(
        xdblbf, 128, dtwbf, DTR_, dtproj_b + (size_t)i*ED_, delta, ED_, DTR_, 2 | 4);
    // chunked scan
    scan_phase1<<<dim3(ED_/8, NCH), blk, 0, stream>>>(
        delta, u_buf, xdbl, A_log + (size_t)i*ED_*NST, hend, pend);
    scan_phase3<<<dim3(ED_/8, NCH), blk, 0, stream>>>(
        delta, u_buf, xdbl, A_log + (size_t)i*ED_*NST, hend, pend,
        Dp + (size_t)i*ED_, xz, ybf);
    // h += y @ out_w^T   (bf16 MFMA, split-K=4)
    f2bf_k<<<1024, blk, 0, stream>>>(out_w + (size_t)i*D_*ED_, wbf, D_*ED_);
    gemm_mfma_sk<<<dim3(D_/128, L_/128, ZSPL), blk, 0, stream>>>(
        ybf, wbf, skmf, L_, D_, ED_, ED_/ZSPL);
    mfma_sk_reduce<<<dim3(L_*D_/4/256), blk, 0, stream>>>(
        skmf, nullptr, h_buf, nullptr, L_*D_, D_, ZSPL, 1);
  }

  layernorm_k<<<L_, blk, 0, stream>>>(h_buf, fn_g, fn_b, out);
  colmean_part_k<<<dim3(D_/256, 32), blk, 0, stream>>>(out, cmpart);
  colmean_fin_k<<<D_/256, blk, 0, stream>>>(cmpart, cmean);
  state_k<<<NST, blk, 0, stream>>>(cmean, sp_w, sp_b, out + (size_t)L_*D_);
}

// Round 11
// 650.446 us; speedup vs baseline: 1.3525x; 1.0356x over previous
//
#include <hip/hip_runtime.h>
#include <math.h>

#define D_    1024
#define ED_   2048
#define NST   32
#define KCONV 4
#define DTR_  64
#define L_    1024
#define NB_   4
#define NCH   8
#define CHUNK (L_ / NCH)
#define ZSPL  4
#define XPZ   16

typedef __bf16 bf16_8 __attribute__((ext_vector_type(8)));
typedef __bf16 bf16_4 __attribute__((ext_vector_type(4)));
typedef float  f32x4  __attribute__((ext_vector_type(4)));

__device__ __forceinline__ float softplus_f(float x) {
  return x > 20.f ? x : log1pf(expf(x));
}
__device__ __forceinline__ float silu_f(float x) {
  return x / (1.f + expf(-x));
}

// XCD-aware bijective remap of a linear workgroup id (nwg % 8 == 0 for all
// our GEMM grids); returns swizzled linear id.
__device__ __forceinline__ int xcd_swz(int lin, int nwg) {
  const int q = nwg >> 3;
  return (lin & 7) * q + (lin >> 3);
}

// segmented fp32 -> bf16 (each count multiple of 8)
__global__ __launch_bounds__(256) void f2bf4_k(
    const float* __restrict__ i0, __bf16* __restrict__ o0, int n0,
    const float* __restrict__ i1, __bf16* __restrict__ o1, int n1,
    const float* __restrict__ i2, __bf16* __restrict__ o2, int n2,
    const float* __restrict__ i3, __bf16* __restrict__ o3, int n3)
{
  int gid = blockIdx.x * 256 + threadIdx.x;
  const int u0 = n0 >> 3, u1 = n1 >> 3, u2 = n2 >> 3, u3 = n3 >> 3;
  const float* in; __bf16* out;
  if (gid < u0) { in = i0; out = o0; }
  else if ((gid -= u0) < u1) { in = i1; out = o1; }
  else if ((gid -= u1) < u2) { in = i2; out = o2; }
  else if ((gid -= u2) < u3) { in = i3; out = o3; }
  else return;
  const int i = gid * 8;
  const float4 a = *reinterpret_cast<const float4*>(in + i);
  const float4 b = *reinterpret_cast<const float4*>(in + i + 4);
  bf16_8 v;
  v[0]=(__bf16)a.x; v[1]=(__bf16)a.y; v[2]=(__bf16)a.z; v[3]=(__bf16)a.w;
  v[4]=(__bf16)b.x; v[5]=(__bf16)b.y; v[6]=(__bf16)b.z; v[7]=(__bf16)b.w;
  *reinterpret_cast<bf16_8*>(out + i) = v;
}

// ---- MFMA bf16 GEMM: C[M,N] = A[M,K](lda) @ W[N,K](ldw)^T ----
// 128x128 tile, BK=64, XOR-swizzled LDS, XCD-swizzled grid.
// flags: 1=accumulate, 2=softplus, 4=bias
__global__ __launch_bounds__(256) void gemm_mfma(
    const __bf16* __restrict__ A, int lda,
    const __bf16* __restrict__ W, int ldw,
    const float* __restrict__ bias, float* __restrict__ C, int ldc,
    int K, int flags)
{
  __shared__ __bf16 As[128 * 64];
  __shared__ __bf16 Ws[128 * 64];
  const int tid  = threadIdx.x;
  const int lane = tid & 63;
  const int w    = tid >> 6;
  const int wr   = w >> 1, wc = w & 1;
  const int nwg  = gridDim.x * gridDim.y;
  const int swz  = xcd_swz(blockIdx.y * gridDim.x + blockIdx.x, nwg);
  const int bx   = swz % gridDim.x, by = swz / gridDim.x;
  const int row0 = by * 128, col0 = bx * 128;

  f32x4 acc[4][4] = {};

  for (int k0 = 0; k0 < K; k0 += 64) {
    #pragma unroll
    for (int j = 0; j < 4; ++j) {
      const int inst = w * 4 + j;
      const int row  = inst * 8 + (lane >> 3);
      const int lu   = (lane & 7) ^ (row & 7);
      __builtin_amdgcn_global_load_lds(
          (const __attribute__((address_space(1))) void*)(A + (size_t)(row0 + row) * lda + k0 + lu * 8),
          (__attribute__((address_space(3))) void*)(&As[inst * 512]), 16, 0, 0);
      __builtin_amdgcn_global_load_lds(
          (const __attribute__((address_space(1))) void*)(W + (size_t)(col0 + row) * ldw + k0 + lu * 8),
          (__attribute__((address_space(3))) void*)(&Ws[inst * 512]), 16, 0, 0);
    }
    __syncthreads();
    const int r16 = lane & 15;
    const int uq  = lane >> 4;
    #pragma unroll
    for (int ks = 0; ks < 2; ++ks) {
      bf16_8 af[4], bfr[4];
      #pragma unroll
      for (int m = 0; m < 4; ++m) {
        const int row = wr * 64 + m * 16 + r16;
        const int pu  = (ks * 4 + uq) ^ (row & 7);
        af[m] = *reinterpret_cast<const bf16_8*>(&As[row * 64 + pu * 8]);
      }
      #pragma unroll
      for (int n = 0; n < 4; ++n) {
        const int row = wc * 64 + n * 16 + r16;
        const int pu  = (ks * 4 + uq) ^ (row & 7);
        bfr[n] = *reinterpret_cast<const bf16_8*>(&Ws[row * 64 + pu * 8]);
      }
      #pragma unroll
      for (int m = 0; m < 4; ++m)
        #pragma unroll
        for (int n = 0; n < 4; ++n)
          acc[m][n] = __builtin_amdgcn_mfma_f32_16x16x32_bf16(af[m], bfr[n], acc[m][n], 0, 0, 0);
    }
    __syncthreads();
  }

  const int crow = (lane >> 4) * 4;
  const int ccol = lane & 15;
  #pragma unroll
  for (int m = 0; m < 4; ++m)
    #pragma unroll
    for (int n = 0; n < 4; ++n) {
      const int col = col0 + wc * 64 + n * 16 + ccol;
      const float bv = (flags & 4) ? bias[col] : 0.f;
      #pragma unroll
      for (int r = 0; r < 4; ++r) {
        const int row = row0 + wr * 64 + m * 16 + crow + r;
        float* cp = C + (size_t)row * ldc + col;
        float v = acc[m][n][r] + bv;
        if (flags & 2) v = softplus_f(v);
        if (flags & 1) v += *cp;
        *cp = v;
      }
    }
}

// split-K MFMA GEMM (lda=ldw=K), BK=64 swizzled, XCD-swizzled grid
__global__ __launch_bounds__(256) void gemm_mfma_sk(
    const __bf16* __restrict__ A, const __bf16* __restrict__ W,
    float* __restrict__ partials, int M, int N, int K, int Kc)
{
  __shared__ __bf16 As[128 * 64];
  __shared__ __bf16 Ws[128 * 64];
  const int tid  = threadIdx.x;
  const int lane = tid & 63;
  const int w    = tid >> 6;
  const int wr   = w >> 1, wc = w & 1;
  const int nwg  = gridDim.x * gridDim.y * gridDim.z;
  const int lin  = (blockIdx.z * gridDim.y + blockIdx.y) * gridDim.x + blockIdx.x;
  const int swz  = xcd_swz(lin, nwg);
  const int bx   = swz % gridDim.x;
  const int tmp  = swz / gridDim.x;
  const int by   = tmp % gridDim.y, bz = tmp / gridDim.y;
  const int row0 = by * 128, col0 = bx * 128;
  const int kbase = bz * Kc;

  f32x4 acc[4][4] = {};

  for (int k0 = kbase; k0 < kbase + Kc; k0 += 64) {
    #pragma unroll
    for (int j = 0; j < 4; ++j) {
      const int inst = w * 4 + j;
      const int row  = inst * 8 + (lane >> 3);
      const int lu   = (lane & 7) ^ (row & 7);
      __builtin_amdgcn_global_load_lds(
          (const __attribute__((address_space(1))) void*)(A + (size_t)(row0 + row) * K + k0 + lu * 8),
          (__attribute__((address_space(3))) void*)(&As[inst * 512]), 16, 0, 0);
      __builtin_amdgcn_global_load_lds(
          (const __attribute__((address_space(1))) void*)(W + (size_t)(col0 + row) * K + k0 + lu * 8),
          (__attribute__((address_space(3))) void*)(&Ws[inst * 512]), 16, 0, 0);
    }
    __syncthreads();
    const int r16 = lane & 15;
    const int uq  = lane >> 4;
    #pragma unroll
    for (int ks = 0; ks < 2; ++ks) {
      bf16_8 af[4], bfr[4];
      #pragma unroll
      for (int m = 0; m < 4; ++m) {
        const int row = wr * 64 + m * 16 + r16;
        const int pu  = (ks * 4 + uq) ^ (row & 7);
        af[m] = *reinterpret_cast<const bf16_8*>(&As[row * 64 + pu * 8]);
      }
      #pragma unroll
      for (int n = 0; n < 4; ++n) {
        const int row = wc * 64 + n * 16 + r16;
        const int pu  = (ks * 4 + uq) ^ (row & 7);
        bfr[n] = *reinterpret_cast<const bf16_8*>(&Ws[row * 64 + pu * 8]);
      }
      #pragma unroll
      for (int m = 0; m < 4; ++m)
        #pragma unroll
        for (int n = 0; n < 4; ++n)
          acc[m][n] = __builtin_amdgcn_mfma_f32_16x16x32_bf16(af[m], bfr[n], acc[m][n], 0, 0, 0);
    }
    __syncthreads();
  }

  float* base = partials + (size_t)bz * M * N;
  const int crow = (lane >> 4) * 4;
  const int ccol = lane & 15;
  #pragma unroll
  for (int m = 0; m < 4; ++m)
    #pragma unroll
    for (int n = 0; n < 4; ++n) {
      const int col = col0 + wc * 64 + n * 16 + ccol;
      #pragma unroll
      for (int r = 0; r < 4; ++r) {
        const int row = row0 + wr * 64 + m * 16 + crow + r;
        base[(size_t)row * N + col] = acc[m][n][r];
      }
    }
}

// reduce nz partials -> C; flags: 1=acc into C, 4=bias(per col), 8=emit bf16 copy
__global__ __launch_bounds__(256) void mfma_sk_reduce(
    const float* __restrict__ partials, const float* __restrict__ bias,
    float* __restrict__ C, __bf16* __restrict__ Cbf,
    int elems, int ncols, int nz, int flags)
{
  const int i = (blockIdx.x * 256 + threadIdx.x) * 4;
  if (i >= elems) return;
  float4 s = *reinterpret_cast<const float4*>(partials + i);
  for (int z = 1; z < nz; ++z) {
    const float4 p = *reinterpret_cast<const float4*>(partials + (size_t)z * elems + i);
    s.x += p.x; s.y += p.y; s.z += p.z; s.w += p.w;
  }
  if (flags & 4) {
    const float4 bv = *reinterpret_cast<const float4*>(bias + (i % ncols));
    s.x += bv.x; s.y += bv.y; s.z += bv.z; s.w += bv.w;
  }
  if (flags & 1) {
    const float4 ov = *reinterpret_cast<const float4*>(C + i);
    s.x += ov.x; s.y += ov.y; s.z += ov.z; s.w += ov.w;
  }
  *reinterpret_cast<float4*>(C + i) = s;
  if (flags & 8) {
    bf16_4 b;
    b[0]=(__bf16)s.x; b[1]=(__bf16)s.y; b[2]=(__bf16)s.z; b[3]=(__bf16)s.w;
    *reinterpret_cast<bf16_4*>(Cbf + i) = b;
  }
}

// layernorm, fp32 out (final LN)
__global__ __launch_bounds__(256) void layernorm_k(
    const float* __restrict__ x, const float* __restrict__ g,
    const float* __restrict__ b, float* __restrict__ out)
{
  __shared__ float red[8];
  const int row = blockIdx.x;
  const int tid = threadIdx.x;
  const float* xr = x + (size_t)row * D_;
  float4 v = *reinterpret_cast<const float4*>(xr + tid * 4);
  float s = v.x + v.y + v.z + v.w;
  #pragma unroll
  for (int off = 32; off; off >>= 1) s += __shfl_down(s, off, 64);
  if ((tid & 63) == 0) red[tid >> 6] = s;
  __syncthreads();
  const float m = (red[0] + red[1] + red[2] + red[3]) * (1.f / D_);
  float dx0 = v.x - m, dx1 = v.y - m, dx2 = v.z - m, dx3 = v.w - m;
  float ss = dx0*dx0 + dx1*dx1 + dx2*dx2 + dx3*dx3;
  #pragma unroll
  for (int off = 32; off; off >>= 1) ss += __shfl_down(ss, off, 64);
  if ((tid & 63) == 0) red[4 + (tid >> 6)] = ss;
  __syncthreads();
  const float var = (red[4] + red[5] + red[6] + red[7]) * (1.f / D_);
  const float rs = rsqrtf(var + 1e-5f);
  const int c = tid * 4;
  const float4 gv = *reinterpret_cast<const float4*>(g + c);
  const float4 bv = *reinterpret_cast<const float4*>(b + c);
  float4 o;
  o.x = dx0 * rs * gv.x + bv.x;
  o.y = dx1 * rs * gv.y + bv.y;
  o.z = dx2 * rs * gv.z + bv.z;
  o.w = dx3 * rs * gv.w + bv.w;
  *reinterpret_cast<float4*>(out + (size_t)row * D_ + c) = o;
}

// layernorm with bf16 out
__global__ __launch_bounds__(256) void layernorm_bf_k(
    const float* __restrict__ x, const float* __restrict__ g,
    const float* __restrict__ b, __bf16* __restrict__ out)
{
  __shared__ float red[8];
  const int row = blockIdx.x;
  const int tid = threadIdx.x;
  const float* xr = x + (size_t)row * D_;
  float4 v = *reinterpret_cast<const float4*>(xr + tid * 4);
  float s = v.x + v.y + v.z + v.w;
  #pragma unroll
  for (int off = 32; off; off >>= 1) s += __shfl_down(s, off, 64);
  if ((tid & 63) == 0) red[tid >> 6] = s;
  __syncthreads();
  const float m = (red[0] + red[1] + red[2] + red[3]) * (1.f / D_);
  float dx0 = v.x - m, dx1 = v.y - m, dx2 = v.z - m, dx3 = v.w - m;
  float ss = dx0*dx0 + dx1*dx1 + dx2*dx2 + dx3*dx3;
  #pragma unroll
  for (int off = 32; off; off >>= 1) ss += __shfl_down(ss, off, 64);
  if ((tid & 63) == 0) red[4 + (tid >> 6)] = ss;
  __syncthreads();
  const float var = (red[4] + red[5] + red[6] + red[7]) * (1.f / D_);
  const float rs = rsqrtf(var + 1e-5f);
  const int c = tid * 4;
  const float4 gv = *reinterpret_cast<const float4*>(g + c);
  const float4 bv = *reinterpret_cast<const float4*>(b + c);
  bf16_4 o;
  o[0] = (__bf16)(dx0 * rs * gv.x + bv.x);
  o[1] = (__bf16)(dx1 * rs * gv.y + bv.y);
  o[2] = (__bf16)(dx2 * rs * gv.z + bv.z);
  o[3] = (__bf16)(dx3 * rs * gv.w + bv.w);
  *reinterpret_cast<bf16_4*>(out + (size_t)row * D_ + c) = o;
}

// depthwise causal conv K=4 + bias + silu; 8 timesteps/thread; fp32 + bf16 out
__global__ __launch_bounds__(256) void conv_silu_k(
    const float* __restrict__ xz, const float* __restrict__ cw,
    const float* __restrict__ cb, float* __restrict__ u, __bf16* __restrict__ ub)
{
  const int e = blockIdx.x * 256 + threadIdx.x;
  const int t0 = blockIdx.y * 8;
  const float w0 = cw[e*4+0], w1 = cw[e*4+1], w2 = cw[e*4+2], w3 = cw[e*4+3];
  const float b = cb[e];
  float x0 = (t0 >= 3) ? xz[(size_t)(t0-3)*(2*ED_)+e] : 0.f;
  float x1 = (t0 >= 2) ? xz[(size_t)(t0-2)*(2*ED_)+e] : 0.f;
  float x2 = (t0 >= 1) ? xz[(size_t)(t0-1)*(2*ED_)+e] : 0.f;
  #pragma unroll
  for (int j = 0; j < 8; ++j) {
    const float x3 = xz[(size_t)(t0+j)*(2*ED_)+e];
    const float uv = silu_f(b + w0*x0 + w1*x1 + w2*x2 + w3*x3);
    u[(size_t)(t0+j)*ED_+e] = uv;
    ub[(size_t)(t0+j)*ED_+e] = (__bf16)uv;
    x0 = x1; x1 = x2; x2 = x3;
  }
}

// ---- chunked selective scan ----
__global__ __launch_bounds__(256) void scan_phase1(
    const float* __restrict__ delta, const float* __restrict__ u,
    const float* __restrict__ xdbl, const float* __restrict__ A_log,
    float* __restrict__ hend, float* __restrict__ Pend)
{
  __shared__ float dl[16][8], ul[16][8];
  __shared__ float bl[16][32];
  const int tid = threadIdx.x;
  const int n = tid & 31;
  const int c = tid >> 5;
  const int e0 = blockIdx.x * 8;
  const int e = e0 + c;
  const int ch = blockIdx.y;
  const float a = -expf(A_log[e * NST + n]);
  float h = 0.f, S = 0.f;
  const int t0 = ch * CHUNK;
  const int s_t = (tid & 127) >> 3, s_e = tid & 7;
  const int b_c = (tid & 7) * 4;

  float rg_a = 0.f;
  float4 rg_b;
  if (tid < 128) {
    rg_a = delta[(size_t)(t0 + s_t) * ED_ + e0 + s_e];
    rg_b = *reinterpret_cast<const float4*>(&xdbl[(size_t)(t0 + s_t) * 128 + 64 + b_c]);
  } else {
    rg_a = u[(size_t)(t0 + s_t) * ED_ + e0 + s_e];
  }

  for (int tb = 0; tb < CHUNK; tb += 16) {
    if (tid < 128) {
      dl[s_t][s_e] = rg_a;
      *reinterpret_cast<float4*>(&bl[s_t][b_c]) = rg_b;
    } else {
      ul[s_t][s_e] = rg_a;
    }
    __syncthreads();
    if (tb + 16 < CHUNK) {
      const int t = t0 + tb + 16 + s_t;
      if (tid < 128) {
        rg_a = delta[(size_t)t * ED_ + e0 + s_e];
        rg_b = *reinterpret_cast<const float4*>(&xdbl[(size_t)t * 128 + 64 + b_c]);
      } else {
        rg_a = u[(size_t)t * ED_ + e0 + s_e];
      }
    }
    #pragma unroll
    for (int j = 0; j < 16; ++j) {
      const float sd = dl[j][c];
      const float uv = ul[j][c];
      const float Bv = bl[j][n];
      h = fmaf(__expf(sd * a), h, sd * uv * Bv);
      S += sd;
    }
    __syncthreads();
  }
  const int idx = ch * (ED_ * NST) + blockIdx.x * 256 + tid;
  hend[idx] = h;
  Pend[idx] = __expf(a * S);
}

// phase 3: inline h_in combine + software-pipelined LDS-staged tiles.
__global__ __launch_bounds__(256, 7) void scan_phase3(
    const float* __restrict__ delta, const float* __restrict__ u,
    const float* __restrict__ xdbl, const float* __restrict__ A_log,
    const float* __restrict__ hend, const float* __restrict__ Pend,
    const float* __restrict__ Dp,
    const float* __restrict__ xz, __bf16* __restrict__ y)
{
  __shared__ float p_lds[8][16][33];
  __shared__ float dl[16][8], ul[16][8], zl[16][8];
  __shared__ float bc[16][64];
  const int tid = threadIdx.x;
  const int n = tid & 31;
  const int c = tid >> 5;
  const int e0 = blockIdx.x * 8;
  const int e = e0 + c;
  const int ch = blockIdx.y;
  const float a = -expf(A_log[e * NST + n]);
  const float dp = Dp[e];

  float h = 0.f;
  {
    const int sidx = blockIdx.x * 256 + tid;
    for (int cc = 0; cc < ch; ++cc) {
      const int off = cc * (ED_ * NST) + sidx;
      h = fmaf(Pend[off], h, hend[off]);
    }
  }

  const int t0 = ch * CHUNK;
  const int r = n & 15, half = n >> 4;
  const int s_t  = (tid & 127) >> 3;
  const int s_e  = tid & 7;
  const int b_t  = tid >> 4;
  const int b_c  = (tid & 15) * 4;

  float rg_a = 0.f, rg_z = 0.f;
  float4 rg_bc;
  {
    const int t = t0 + s_t;
    if (tid < 128) {
      rg_a = delta[(size_t)t * ED_ + e0 + s_e];
      rg_z = xz[(size_t)t * (2*ED_) + ED_ + e0 + s_e];
    } else {
      rg_a = u[(size_t)t * ED_ + e0 + s_e];
    }
    rg_bc = *reinterpret_cast<const float4*>(&xdbl[(size_t)(t0 + b_t) * 128 + 64 + b_c]);
  }

  for (int tb = 0; tb < CHUNK; tb += 16) {
    if (tid < 128) { dl[s_t][s_e] = rg_a; zl[s_t][s_e] = rg_z; }
    else          { ul[s_t][s_e] = rg_a; }
    *reinterpret_cast<float4*>(&bc[b_t][b_c]) = rg_bc;
    __syncthreads();
    if (tb + 16 < CHUNK) {
      const int t = t0 + tb + 16 + s_t;
      if (tid < 128) {
        rg_a = delta[(size_t)t * ED_ + e0 + s_e];
        rg_z = xz[(size_t)t * (2*ED_) + ED_ + e0 + s_e];
      } else {
        rg_a = u[(size_t)t * ED_ + e0 + s_e];
      }
      rg_bc = *reinterpret_cast<const float4*>(&xdbl[(size_t)(t0 + tb + 16 + b_t) * 128 + 64 + b_c]);
    }
    #pragma unroll
    for (int j = 0; j < 16; ++j) {
      const float sd = dl[j][c];
      const float uv = ul[j][c];
      const float Bv = bc[j][n];
      const float Cv = bc[j][32 + n];
      const float dA = __expf(sd * a);
      h = fmaf(dA, h, sd * uv * Bv);
      p_lds[c][j][n] = h * Cv;
    }
    __syncthreads();
    float s = 0.f;
    #pragma unroll
    for (int k = 0; k < 16; ++k) s += p_lds[c][r][half * 16 + k];
    s += __shfl_xor(s, 16, 64);
    if (half == 0) {
      const float uvt = ul[r][c];
      const float zv  = zl[r][c];
      y[(size_t)(t0 + tb + r) * ED_ + e] = (__bf16)((s + uvt * dp) * silu_f(zv));
    }
    __syncthreads();
  }
}

// column-mean partials (coalesced)
__global__ __launch_bounds__(256) void colmean_part_k(
    const float* __restrict__ hf, float* __restrict__ part)
{
  const int d = blockIdx.x * 256 + threadIdx.x;
  const int tc = blockIdx.y;
  float s = 0.f;
  #pragma unroll 8
  for (int j = 0; j < 32; ++j) s += hf[(size_t)(tc * 32 + j) * D_ + d];
  part[tc * D_ + d] = s;
}

// fused finalize + state projection: block = one of 32 output features
__global__ __launch_bounds__(256) void state_fused_k(
    const float* __restrict__ part, const float* __restrict__ spw,
    const float* __restrict__ spb, float* __restrict__ out)
{
  __shared__ float red[4];
  const int nidx = blockIdx.x;
  const int tid = threadIdx.x;
  float s = 0.f;
  for (int d = tid; d < D_; d += 256) {
    float cm = 0.f;
    #pragma unroll
    for (int c = 0; c < 32; ++c) cm += part[c * D_ + d];
    s += cm * (1.f / L_) * spw[(size_t)nidx * D_ + d];
  }
  #pragma unroll
  for (int off = 32; off; off >>= 1) s += __shfl_down(s, off, 64);
  if ((tid & 63) == 0) red[tid >> 6] = s;
  __syncthreads();
  if (tid == 0) out[nidx] = red[0] + red[1] + red[2] + red[3] + spb[nidx];
}

extern "C" void kernel_launch(void* const* d_in, const int* in_sizes, int n_in,
                              void* d_out, int out_size, void* d_ws, size_t ws_size,
                              hipStream_t stream) {
  const float* x        = (const float*)d_in[0];
  const float* Wi       = (const float*)d_in[1];
  const float* bi       = (const float*)d_in[2];
  const float* ln_g     = (const float*)d_in[3];
  const float* ln_b     = (const float*)d_in[4];
  const float* in_w     = (const float*)d_in[5];
  const float* conv_w   = (const float*)d_in[6];
  const float* conv_b   = (const float*)d_in[7];
  const float* xproj_w  = (const float*)d_in[8];
  const float* dtproj_w = (const float*)d_in[9];
  const float* dtproj_b = (const float*)d_in[10];
  const float* A_log    = (const float*)d_in[11];
  const float* Dp       = (const float*)d_in[12];
  const float* out_w    = (const float*)d_in[13];
  const float* fn_g     = (const float*)d_in[14];
  const float* fn_b     = (const float*)d_in[15];
  const float* sp_w     = (const float*)d_in[16];
  const float* sp_b     = (const float*)d_in[17];
  float* out  = (float*)d_out;
  float* ws_f = (float*)d_ws;

  float* h_buf  = ws_f;                // 1048576
  float* xz     = ws_f + 1048576;      // 4194304
  float* u_buf  = ws_f + 5242880;      // 2097152
  float* xdbl   = ws_f + 7340032;      // 131072
  float* delta  = ws_f + 7471104;      // 2097152 (also xproj partials)
  float* hend   = ws_f + 9568256;      // 524288
  float* pend   = ws_f + 10092544;     // 524288
  __bf16* nbf   = (__bf16*)(ws_f + 10617856);  // 1M bf16
  __bf16* ybf   = (__bf16*)(ws_f + 11142144);  // 2M bf16
  __bf16* wbf   = (__bf16*)(ws_f + 12190720);  // 8M bf16 (in_w)
  __bf16* xdblbf= (__bf16*)(ws_f + 16385024);  // 128K bf16
  __bf16* dtwbf = (__bf16*)(ws_f + 16450560);  // 128K bf16
  __bf16* ubf   = (__bf16*)(ws_f + 16516096);  // 2M bf16
  __bf16* xpbf  = (__bf16*)(ws_f + 17564672);  // 256K bf16
  __bf16* owbf  = (__bf16*)(ws_f + 17695744);  // 2M bf16 (out_w)
  float* skmf   = u_buf;               // MFMA split-K partials overlay (Wi/out)
  float* skxp   = delta;               // xproj split-K partials overlay
  float* cmpart = hend;                // colmean partials overlay

  const dim3 blk(256);

  // prologue: convert x + Wi in one launch; Wi GEMM split-K=4
  f2bf4_k<<<1024, blk, 0, stream>>>(x, nbf, L_*D_, Wi, wbf, D_*D_,
                                    x, nbf, 0, x, nbf, 0);
  gemm_mfma_sk<<<dim3(D_/128, L_/128, ZSPL), blk, 0, stream>>>(
      nbf, wbf, skmf, L_, D_, D_, D_/ZSPL);
  mfma_sk_reduce<<<dim3(L_*D_/4/256), blk, 0, stream>>>(
      skmf, bi, h_buf, nullptr, L_*D_, D_, ZSPL, 4);

  for (int i = 0; i < NB_; ++i) {
    // convert all 4 weight tensors for this block in ONE launch
    // counts: in_w 4.19M, xproj 262K, dtw 131K, out_w 2.10M -> 6.68M elems
    f2bf4_k<<<3264, blk, 0, stream>>>(
        in_w    + (size_t)i*2*ED_*D_, wbf,   2*ED_*D_,
        xproj_w + (size_t)i*128*ED_,  xpbf,  128*ED_,
        dtproj_w+ (size_t)i*ED_*DTR_, dtwbf, ED_*DTR_,
        out_w   + (size_t)i*D_*ED_,   owbf,  D_*ED_);
    layernorm_bf_k<<<L_, blk, 0, stream>>>(h_buf, ln_g + i*D_, ln_b + i*D_, nbf);
    // xz = normed @ in_w^T
    gemm_mfma<<<dim3(2*ED_/128, L_/128), blk, 0, stream>>>(
        nbf, D_, wbf, D_, nullptr, xz, 2*ED_, D_, 0);
    conv_silu_k<<<dim3(ED_/256, L_/8), blk, 0, stream>>>(
        xz, conv_w + (size_t)i*ED_*KCONV, conv_b + (size_t)i*ED_, u_buf, ubf);
    // x_dbl = u @ xproj^T  (bf16 MFMA split-K=16)
    gemm_mfma_sk<<<dim3(1, L_/128, XPZ), blk, 0, stream>>>(
        ubf, xpbf, skxp, L_, 128, ED_, ED_/XPZ);
    mfma_sk_reduce<<<dim3(L_*128/4/256), blk, 0, stream>>>(
        skxp, nullptr, xdbl, xdblbf, L_*128, 128, XPZ, 8);
    // delta = softplus(dt @ dtproj^T + b)  (bf16 MFMA, K=64)
    gemm_mfma<<<dim3(ED_/128, L_/128), blk, 0, stream>>>(
        xdblbf, 128, dtwbf, DTR_, dtproj_b + (size_t)i*ED_, delta, ED_, DTR_, 2 | 4);
    // chunked scan
    scan_phase1<<<dim3(ED_/8, NCH), blk, 0, stream>>>(
        delta, u_buf, xdbl, A_log + (size_t)i*ED_*NST, hend, pend);
    scan_phase3<<<dim3(ED_/8, NCH), blk, 0, stream>>>(
        delta, u_buf, xdbl, A_log + (size_t)i*ED_*NST, hend, pend,
        Dp + (size_t)i*ED_, xz, ybf);
    // h += y @ out_w^T   (bf16 MFMA, split-K=4)
    gemm_mfma_sk<<<dim3(D_/128, L_/128, ZSPL), blk, 0, stream>>>(
        ybf, owbf, skmf, L_, D_, ED_, ED_/ZSPL);
    mfma_sk_reduce<<<dim3(L_*D_/4/256), blk, 0, stream>>>(
        skmf, nullptr, h_buf, nullptr, L_*D_, D_, ZSPL, 1);
  }

  layernorm_k<<<L_, blk, 0, stream>>>(h_buf, fn_g, fn_b, out);
  colmean_part_k<<<dim3(D_/256, 32), blk, 0, stream>>>(out, cmpart);
  state_fused_k<<<NST, blk, 0, stream>>>(cmpart, sp_w, sp_b, out + (size_t)L_*D_);
}